// Round 4
// baseline (5222.886 us; speedup 1.0000x reference)
//
#include <hip/hip_runtime.h>

typedef unsigned short u16;
typedef __attribute__((ext_vector_type(4))) unsigned short u16x4;
typedef __attribute__((ext_vector_type(8))) unsigned short u16x8;
typedef __attribute__((ext_vector_type(8))) __bf16 bf16x8;
typedef __attribute__((ext_vector_type(4))) float f32x4;

#define DEV __device__ __forceinline__

DEV float b2f(u16 u){ union{ unsigned int i; float f; } x; x.i = ((unsigned int)u) << 16; return x.f; }
DEV u16 f2b(float f){ unsigned int x = __float_as_uint(f); return (u16)((x + 0x7fffu + ((x >> 16) & 1u)) >> 16); }

// ---------------------------------------------------------------- block reduce (256 thr)
DEV void block_red2(float& s, float& q){
#pragma unroll
  for (int off = 32; off; off >>= 1){ s += __shfl_down(s, off); q += __shfl_down(q, off); }
  __shared__ float sh1[4], sh2[4];
  int lane = threadIdx.x & 63, w = threadIdx.x >> 6;
  if (lane == 0){ sh1[w] = s; sh2[w] = q; }
  __syncthreads();
  s = sh1[0] + sh1[1] + sh1[2] + sh1[3];
  q = sh2[0] + sh2[1] + sh2[2] + sh2[3];
}

// ---------------------------------------------------------------- GEMM  C = A[M,K] * B[N,K]^T
// bf16 in, fp32 accumulate, bf16/fp32 out.  2D batch (b,h) via grid.z (z = b*Hh + h).
template<int WM, int WN, bool OUTB>
__global__ __launch_bounds__(WM*WN*64) void gemm_bt(
    const u16* __restrict__ A, const u16* __restrict__ Bm, void* __restrict__ Cp,
    int K, int lda, int ldb, int ldc, int Hh,
    long aob, long aoh, long bob, long boh, long cob, long coh)
{
  constexpr int BM = WM*64, BN = WN*64, BK = 64, LSTR = BK + 8;
  __shared__ u16 At[BM*LSTR];
  __shared__ u16 Bt[BN*LSTR];
  int z = blockIdx.z, b_ = z / Hh, h_ = z % Hh;
  const u16* Ab = A + (long)b_*aob + (long)h_*aoh;
  const u16* Bb = Bm + (long)b_*bob + (long)h_*boh;
  long cbase = (long)b_*cob + (long)h_*coh;
  int m0 = blockIdx.y * BM, n0 = blockIdx.x * BN;
  int tid = threadIdx.x, lane = tid & 63, wv = tid >> 6;
  int wm = wv / WN, wn = wv % WN;
  constexpr int T = WM*WN*64;
  f32x4 acc[4][4];
  f32x4 z4 = {0.f, 0.f, 0.f, 0.f};
#pragma unroll
  for (int a = 0; a < 4; a++)
#pragma unroll
    for (int b = 0; b < 4; b++) acc[a][b] = z4;
  int lr = lane & 15, lk8 = (lane >> 4) * 8;
  for (int k0 = 0; k0 < K; k0 += BK){
    __syncthreads();
    for (int idx = tid; idx < BM*8; idx += T){
      int r = idx >> 3, c = (idx & 7) << 3;
      *(u16x8*)&At[r*LSTR + c] = *(const u16x8*)&Ab[(long)(m0 + r)*lda + k0 + c];
    }
    for (int idx = tid; idx < BN*8; idx += T){
      int r = idx >> 3, c = (idx & 7) << 3;
      *(u16x8*)&Bt[r*LSTR + c] = *(const u16x8*)&Bb[(long)(n0 + r)*ldb + k0 + c];
    }
    __syncthreads();
#pragma unroll
    for (int kk = 0; kk < BK; kk += 32){
      bf16x8 af[4], bfr[4];
#pragma unroll
      for (int mi = 0; mi < 4; mi++) af[mi]  = *(bf16x8*)&At[(wm*64 + mi*16 + lr)*LSTR + kk + lk8];
#pragma unroll
      for (int ni = 0; ni < 4; ni++) bfr[ni] = *(bf16x8*)&Bt[(wn*64 + ni*16 + lr)*LSTR + kk + lk8];
#pragma unroll
      for (int mi = 0; mi < 4; mi++)
#pragma unroll
        for (int ni = 0; ni < 4; ni++)
          acc[mi][ni] = __builtin_amdgcn_mfma_f32_16x16x32_bf16(af[mi], bfr[ni], acc[mi][ni], 0, 0, 0);
    }
  }
  int orow = (lane >> 4) * 4, ocol = lane & 15;
#pragma unroll
  for (int mi = 0; mi < 4; mi++)
#pragma unroll
    for (int ni = 0; ni < 4; ni++){
      int row = m0 + wm*64 + mi*16 + orow;
      int col = n0 + wn*64 + ni*16 + ocol;
      long cidx = cbase + (long)row*ldc + col;
#pragma unroll
      for (int r = 0; r < 4; r++){
        float vv = acc[mi][ni][r];
        if (OUTB) ((u16*)Cp)[cidx + (long)r*ldc] = f2b(vv);
        else      ((float*)Cp)[cidx + (long)r*ldc] = vv;
      }
    }
}

// ---------------------------------------------------------------- bf16 transpose dst[c,r]=src[r,c]
__global__ __launch_bounds__(256) void transpose_k(
    const u16* __restrict__ src, u16* __restrict__ dst,
    int lds_, int ldd, int Hh, long sob, long soh, long dob, long doh)
{
  __shared__ u16 tile[64*72];
  int z = blockIdx.z, b_ = z / Hh, h_ = z % Hh;
  const u16* S_ = src + (long)b_*sob + (long)h_*soh;
  u16* D_ = dst + (long)b_*dob + (long)h_*doh;
  int r0 = blockIdx.y * 64, c0 = blockIdx.x * 64;
  int tid = threadIdx.x;
  for (int idx = tid; idx < 512; idx += 256){
    int r = idx >> 3, c = (idx & 7) << 3;
    *(u16x8*)&tile[r*72 + c] = *(const u16x8*)&S_[(long)(r0 + r)*lds_ + c0 + c];
  }
  __syncthreads();
  for (int idx = tid; idx < 512; idx += 256){
    int c = idx >> 3, r = (idx & 7) << 3;
    u16x8 v;
#pragma unroll
    for (int e = 0; e < 8; e++) v[e] = tile[(r + e)*72 + c];
    *(u16x8*)&D_[(long)(c0 + c)*ldd + r0 + r] = v;
  }
}

// ---------------------------------------------------------------- fp32 src -> bf16 transposed dst
__global__ __launch_bounds__(256) void transpose_cvt_k(
    const float* __restrict__ src, u16* __restrict__ dst, int lds_, int ldd)
{
  __shared__ u16 tile[64*72];
  int r0 = blockIdx.y * 64, c0 = blockIdx.x * 64;
  int tid = threadIdx.x;
  for (int idx = tid; idx < 512; idx += 256){
    int r = idx >> 3, c = (idx & 7) << 3;
    const float* s = &src[(long)(r0 + r)*lds_ + c0 + c];
#pragma unroll
    for (int e = 0; e < 8; e++) tile[r*72 + c + e] = f2b(s[e]);
  }
  __syncthreads();
  for (int idx = tid; idx < 512; idx += 256){
    int c = idx >> 3, r = (idx & 7) << 3;
    u16x8 v;
#pragma unroll
    for (int e = 0; e < 8; e++) v[e] = tile[(r + e)*72 + c];
    *(u16x8*)&dst[(long)(c0 + c)*ldd + r0 + r] = v;
  }
}

// ---------------------------------------------------------------- flat fp32 -> bf16
__global__ __launch_bounds__(256) void cvt_k(const float* __restrict__ src, u16* __restrict__ dst)
{
  long i = ((long)blockIdx.x*256 + threadIdx.x) * 4;
  float4 v = *(const float4*)&src[i];
  u16x4 o; o[0] = f2b(v.x); o[1] = f2b(v.y); o[2] = f2b(v.z); o[3] = f2b(v.w);
  *(u16x4*)&dst[i] = o;
}

// ---------------------------------------------------------------- LayerNorm row=1024, fp32 in, bf16 out
__global__ __launch_bounds__(256) void ln_k(const float* __restrict__ src, const float* __restrict__ g,
                                            const float* __restrict__ be, u16* __restrict__ out)
{
  long base = (long)blockIdx.x * 1024;
  int tid = threadIdx.x;
  const float* s = src + base + tid*4;
  float v[4] = {s[0], s[1], s[2], s[3]};
  float s1 = v[0]+v[1]+v[2]+v[3];
  float s2 = v[0]*v[0]+v[1]*v[1]+v[2]*v[2]+v[3]*v[3];
  block_red2(s1, s2);
  float mu = s1 * (1.f/1024.f);
  float var = s2 * (1.f/1024.f) - mu*mu;
  float rs = rsqrtf(var + 1e-5f);
#pragma unroll
  for (int e = 0; e < 4; e++){
    int col = tid*4 + e;
    out[base + col] = f2b((v[e]-mu)*rs*g[col] + be[col]);
  }
}

// ---------------------------------------------------------------- out = resid + LN(go + xn + bias)  (fp32 out)
__global__ __launch_bounds__(256) void add_ln_k(const float* __restrict__ go, const u16* __restrict__ xn,
    const float* __restrict__ bias, const float* __restrict__ g, const float* __restrict__ be,
    const float* __restrict__ resid, float* __restrict__ outp)
{
  long base = (long)blockIdx.x * 1024;
  int tid = threadIdx.x;
  float v[4];
#pragma unroll
  for (int e = 0; e < 4; e++){
    int col = tid*4 + e;
    v[e] = go[base + col] + b2f(xn[base + col]) + bias[col];
  }
  float s1 = v[0]+v[1]+v[2]+v[3];
  float s2 = v[0]*v[0]+v[1]*v[1]+v[2]*v[2]+v[3]*v[3];
  block_red2(s1, s2);
  float mu = s1 * (1.f/1024.f);
  float var = s2 * (1.f/1024.f) - mu*mu;
  float rs = rsqrtf(var + 1e-5f);
#pragma unroll
  for (int e = 0; e < 4; e++){
    int col = tid*4 + e;
    outp[base + col] = resid[base + col] + (v[e]-mu)*rs*g[col] + be[col];
  }
}

// ---------------------------------------------------------------- QQ = [q+u | shifted(q+v)]  (B,S,H,128)
__global__ __launch_bounds__(256) void build_qq(const u16* __restrict__ q, const float* __restrict__ u,
                                                const float* __restrict__ v, u16* __restrict__ QQ)
{
  int bi = blockIdx.x;                       // bi = b*1024 + i
  long qrow = (long)bi * 1024;
  long obase = (long)bi * 2048;
  // rel_shift source: n = bi + B ; b'=n/(S+1) ; i'=n%(S+1) ; zero row if i'==0
  int n = bi + 2;
  int bp = n / 1025, ip = n % 1025;
  long qsrc = ip ? ((long)(bp*1024 + ip - 1)) * 1024 : -1;
  for (int t = threadIdx.x; t < 2048; t += 256){
    int h = t >> 7, e = t & 127;
    float val;
    if (e < 64) val = b2f(q[qrow + h*64 + e]) + u[h*64 + e];
    else {
      int d = e - 64;
      val = (qsrc < 0) ? 0.f : b2f(q[qsrc + h*64 + d]) + v[h*64 + d];
    }
    QQ[obase + t] = f2b(val);
  }
}

// ---------------------------------------------------------------- BB = [k | pos_emb]  (B,St,H,128)
__global__ __launch_bounds__(256) void build_bb(const u16* __restrict__ kv, const float* __restrict__ pe,
                                                u16* __restrict__ BB)
{
  int bj = blockIdx.x;                       // bj = b*2048 + j
  int j = bj & 2047;
  long kvrow = (long)bj * 2048;
  long obase = (long)bj * 2048;
  for (int t = threadIdx.x; t < 2048; t += 256){
    int h = t >> 7, e = t & 127;
    u16 val = (e < 64) ? kv[kvrow + h*64 + e] : f2b(pe[(long)j*1024 + h*64 + (e - 64)]);
    BB[obase + t] = val;
  }
}

// ---------------------------------------------------------------- query-axis softmax, in place (bf16)
__global__ __launch_bounds__(256) void softmax_q(u16* __restrict__ sc, int Sr, int Nc, int Mctx,
                                                 int maskon, float scale)
{
  long base = (long)blockIdx.y * (long)Sr * Nc;
  int j = blockIdx.x*256 + threadIdx.x;
  u16* p = sc + base + j;
  int i0 = 0;
  if (maskon){ i0 = j - Mctx; if (i0 < 0) i0 = 0; }   // masked: j > i + M  <=>  i < j - M
  float mmax = -3.0e38f, ssum = 0.f;
  for (int i = i0; i < Sr; i++){
    float a = b2f(p[(long)i*Nc]) * scale;
    float nm = fmaxf(mmax, a);
    ssum = ssum * __expf(mmax - nm) + __expf(a - nm);
    mmax = nm;
  }
  float inv = 1.f / ssum;
  for (int i = 0; i < i0; i++) p[(long)i*Nc] = 0;
  for (int i = i0; i < Sr; i++){
    float a = b2f(p[(long)i*Nc]) * scale;
    p[(long)i*Nc] = f2b(__expf(a - mmax) * inv);
  }
}

// ---------------------------------------------------------------- gelu(exact) + bias, fp32 in, bf16 out
__global__ __launch_bounds__(256) void gelu_k(const float* __restrict__ f1, const float* __restrict__ b1,
                                              u16* __restrict__ h1)
{
  long i = (long)blockIdx.x*256 + threadIdx.x;
  float x = f1[i] + b1[i & 4095];
  h1[i] = f2b(0.5f * x * (1.f + erff(x * 0.70710678118654752f)));
}

// ---------------------------------------------------------------- out3 = out2 + f2 + b2  (fp32 out)
__global__ __launch_bounds__(256) void final_k(const float* __restrict__ out2, const float* __restrict__ f2,
                                               const float* __restrict__ b2v, float* __restrict__ outp)
{
  long i = (long)blockIdx.x*256 + threadIdx.x;
  outp[i] = out2[i] + f2[i] + b2v[i & 1023];
}

// ================================================================ host
extern "C" void kernel_launch(void* const* d_in, const int* in_sizes, int n_in,
                              void* d_out, int out_size, void* d_ws, size_t ws_size,
                              hipStream_t stream)
{
  (void)in_sizes; (void)n_in; (void)out_size; (void)ws_size;
  // B=2 S=1024 M=1024 St=2048 D=DI=1024 H=16 DH=64 DFF=4096 ; ALL inputs/output fp32
  const float* X    = (const float*)d_in[0];
  const float* ENC  = (const float*)d_in[1];
  const float* PE   = (const float*)d_in[2];
  const float* Uu   = (const float*)d_in[3];
  const float* Vv   = (const float*)d_in[4];
  const float* MEM  = (const float*)d_in[5];
  const float* WQM  = (const float*)d_in[7];
  const float* WKVM = (const float*)d_in[8];
  const float* FCWM = (const float*)d_in[9];
  const float* FCBM = (const float*)d_in[10];
  const float* LNMG = (const float*)d_in[11];
  const float* LNMB = (const float*)d_in[12];
  const float* WQC  = (const float*)d_in[13];
  const float* WKVC = (const float*)d_in[14];
  const float* FCWC = (const float*)d_in[15];
  const float* FCBC = (const float*)d_in[16];
  const float* LNCG = (const float*)d_in[17];
  const float* LNCB = (const float*)d_in[18];
  const float* W1   = (const float*)d_in[19];
  const float* B1   = (const float*)d_in[20];
  const float* W2   = (const float*)d_in[21];
  const float* B2   = (const float*)d_in[22];
  const float* LN1G = (const float*)d_in[23];
  const float* LN1B = (const float*)d_in[24];
  const float* LN2G = (const float*)d_in[25];
  const float* LN2B = (const float*)d_in[26];
  const float* LN3G = (const float*)d_in[27];
  const float* LN3B = (const float*)d_in[28];
  float* OUT = (float*)d_out;
  char* W = (char*)d_ws;
  const size_t MB = 1ull << 20;

  // ---- lifetime-overlapped layout, peak 120 MB
  // [0,8)    rotating weight region (bf16): MHA wq/wkv/fcw -> cross wq/wkv/fcw -> w1T
  // [8,12)   xn1
  // [12,16)  q -> o_b
  // [16,32)  kv -> ofc [16,24) + outb [24,32)
  // [32,40)  QQ -> xn2 [32,36) + qc [36,40)
  // [40,56)  BB -> kvc [40,48) + Vtc [48,52) + oc [52,56)
  // [56,64)  Vt -> w2T
  // [64,96)  memb/encb [64,68) ; sc 32MB ; f1 [64,96) -> f2 [64,72)
  // [96,112) h1
  // [112,120) out2b (fp32)
  u16*   wT_a  = (u16*)(W + 0*MB);
  u16*   wT_b  = (u16*)(W + 2*MB);
  u16*   wT_c  = (u16*)(W + 6*MB);
  u16*   w1T   = (u16*)(W + 0*MB);
  u16*   xn1   = (u16*)(W + 8*MB);
  u16*   q     = (u16*)(W + 12*MB);
  u16*   o_b   = (u16*)(W + 12*MB);
  u16*   kv    = (u16*)(W + 16*MB);
  float* ofc   = (float*)(W + 16*MB);
  float* outb  = (float*)(W + 24*MB);
  u16*   QQ    = (u16*)(W + 32*MB);
  u16*   xn2   = (u16*)(W + 32*MB);
  u16*   qc    = (u16*)(W + 36*MB);
  u16*   BB    = (u16*)(W + 40*MB);
  u16*   kvc   = (u16*)(W + 40*MB);
  u16*   Vtc   = (u16*)(W + 48*MB);
  u16*   oc    = (u16*)(W + 52*MB);
  u16*   Vt    = (u16*)(W + 56*MB);
  u16*   w2T   = (u16*)(W + 56*MB);
  u16*   memb  = (u16*)(W + 64*MB);
  u16*   encb  = (u16*)(W + 64*MB);
  u16*   sc    = (u16*)(W + 64*MB);
  float* f1    = (float*)(W + 64*MB);
  float* f2    = (float*)(W + 64*MB);
  u16*   h1    = (u16*)(W + 96*MB);
  float* out2b = (float*)(W + 112*MB);

  // ================= MHA (Transformer-XL relative attention) =================
  transpose_cvt_k<<<dim3(16,16),256,0,stream>>>(WQM,  wT_a, 1024,1024);
  transpose_cvt_k<<<dim3(32,16),256,0,stream>>>(WKVM, wT_b, 2048,1024);
  transpose_cvt_k<<<dim3(16,16),256,0,stream>>>(FCWM, wT_c, 1024,1024);
  cvt_k<<<2048,256,0,stream>>>(MEM, memb);       // 2M elems
  ln_k<<<2048,256,0,stream>>>(X, LN1G, LN1B, xn1);
  gemm_bt<2,2,true><<<dim3(8,16,1),256,0,stream>>>(xn1, wT_a, q, 1024, 1024,1024,1024, 1, 0,0,0,0,0,0);
  // kv = [mem ; xn1] @ Wkv_m  (rows 0..1023 = mem, 1024..2047 = xn1, per b)
  gemm_bt<2,2,true><<<dim3(16,8,2),256,0,stream>>>(memb, wT_b, kv, 1024, 1024,1024,2048, 1,
      1048576,0, 0,0, 4194304,0);
  gemm_bt<2,2,true><<<dim3(16,8,2),256,0,stream>>>(xn1, wT_b, kv + (size_t)1024*2048, 1024, 1024,1024,2048, 1,
      1048576,0, 0,0, 4194304,0);
  build_qq<<<2048,256,0,stream>>>(q, Uu, Vv, QQ);
  build_bb<<<4096,256,0,stream>>>(kv, PE, BB);
  transpose_k<<<dim3(1,32,32),256,0,stream>>>(kv + 1024, Vt, 2048, 2048, 16,
      4194304,64, 2097152,131072);
  for (int b = 0; b < 2; b++)
    for (int hc = 0; hc < 2; hc++){
      // scores (content + shifted pos) = QQ @ BB^T, K=128, heads hc*8..hc*8+7 (32 MB)
      gemm_bt<2,2,true><<<dim3(16,8,8),256,0,stream>>>(
          QQ + (size_t)b*2097152 + hc*1024, BB + (size_t)b*4194304 + hc*1024, sc,
          128, 2048,2048,2048, 8, 0,128, 0,128, 0,2097152);
      softmax_q<<<dim3(8,8),256,0,stream>>>(sc, 1024, 2048, 1024, 1, 0.125f);
      gemm_bt<2,1,true><<<dim3(1,8,8),128,0,stream>>>(
          sc, Vt + (size_t)b*2097152 + (size_t)hc*8*131072, o_b + (size_t)b*1048576 + hc*512,
          2048, 2048,2048,1024, 8, 0,2097152, 0,131072, 0,64);
    }
  gemm_bt<2,2,false><<<dim3(8,16,1),256,0,stream>>>(o_b, wT_c, ofc, 1024, 1024,1024,1024, 1, 0,0,0,0,0,0);
  add_ln_k<<<2048,256,0,stream>>>(ofc, xn1, FCBM, LNMG, LNMB, X, outb);

  // ================= cross attention =================
  transpose_cvt_k<<<dim3(16,16),256,0,stream>>>(WQC,  wT_a, 1024,1024);
  transpose_cvt_k<<<dim3(32,16),256,0,stream>>>(WKVC, wT_b, 2048,1024);
  transpose_cvt_k<<<dim3(16,16),256,0,stream>>>(FCWC, wT_c, 1024,1024);
  cvt_k<<<2048,256,0,stream>>>(ENC, encb);       // 2M elems
  ln_k<<<2048,256,0,stream>>>(outb, LN2G, LN2B, xn2);
  gemm_bt<2,2,true><<<dim3(8,16,1),256,0,stream>>>(xn2, wT_a, qc, 1024, 1024,1024,1024, 1, 0,0,0,0,0,0);
  gemm_bt<2,2,true><<<dim3(16,16,1),256,0,stream>>>(encb, wT_b, kvc, 1024, 1024,1024,2048, 1, 0,0,0,0,0,0);
  transpose_k<<<dim3(1,16,32),256,0,stream>>>(kvc + 1024, Vtc, 2048, 1024, 16,
      2097152,64, 1048576,65536);
  for (int b = 0; b < 2; b++){
    gemm_bt<2,2,true><<<dim3(8,8,16),256,0,stream>>>(
        qc + (size_t)b*1048576, kvc + (size_t)b*2097152, sc,
        64, 1024,2048,1024, 16, 0,64, 0,64, 0,1048576);
    softmax_q<<<dim3(4,16),256,0,stream>>>(sc, 1024, 1024, 0, 0, 0.125f);
    gemm_bt<2,1,true><<<dim3(1,8,16),128,0,stream>>>(
        sc, Vtc + (size_t)b*1048576, oc + (size_t)b*1048576,
        1024, 1024,1024,1024, 16, 0,1048576, 0,65536, 0,64);
  }
  gemm_bt<2,2,false><<<dim3(8,16,1),256,0,stream>>>(oc, wT_c, ofc, 1024, 1024,1024,1024, 1, 0,0,0,0,0,0);
  add_ln_k<<<2048,256,0,stream>>>(ofc, xn2, FCBC, LNCG, LNCB, outb, out2b);

  // ================= FFN =================
  transpose_cvt_k<<<dim3(64,16),256,0,stream>>>(W1, w1T, 4096,1024);
  transpose_cvt_k<<<dim3(16,64),256,0,stream>>>(W2, w2T, 1024,4096);
  ln_k<<<2048,256,0,stream>>>(out2b, LN3G, LN3B, xn2);   // xn3 reuses xn2 slot
  gemm_bt<2,2,false><<<dim3(32,16,1),256,0,stream>>>(xn2, w1T, f1, 1024, 1024,1024,4096, 1, 0,0,0,0,0,0);
  gelu_k<<<32768,256,0,stream>>>(f1, B1, h1);
  gemm_bt<2,2,false><<<dim3(8,16,1),256,0,stream>>>(h1, w2T, f2, 4096, 4096,4096,1024, 1, 0,0,0,0,0,0);
  final_k<<<8192,256,0,stream>>>(out2b, f2, B2, OUT);
}

// Round 5
// 2663.141 us; speedup vs baseline: 1.9612x; 1.9612x over previous
//
#include <hip/hip_runtime.h>

typedef unsigned short u16;
typedef __attribute__((ext_vector_type(4))) unsigned short u16x4;
typedef __attribute__((ext_vector_type(8))) unsigned short u16x8;
typedef __attribute__((ext_vector_type(8))) __bf16 bf16x8;
typedef __attribute__((ext_vector_type(4))) float f32x4;

#define DEV __device__ __forceinline__

DEV float b2f(u16 u){ union{ unsigned int i; float f; } x; x.i = ((unsigned int)u) << 16; return x.f; }
DEV u16 f2b(float f){ unsigned int x = __float_as_uint(f); return (u16)((x + 0x7fffu + ((x >> 16) & 1u)) >> 16); }

// ---------------------------------------------------------------- block reduce (256 thr)
DEV void block_red2(float& s, float& q){
#pragma unroll
  for (int off = 32; off; off >>= 1){ s += __shfl_down(s, off); q += __shfl_down(q, off); }
  __shared__ float sh1[4], sh2[4];
  int lane = threadIdx.x & 63, w = threadIdx.x >> 6;
  if (lane == 0){ sh1[w] = s; sh2[w] = q; }
  __syncthreads();
  s = sh1[0] + sh1[1] + sh1[2] + sh1[3];
  q = sh2[0] + sh2[1] + sh2[2] + sh2[3];
}

// ---------------------------------------------------------------- GEMM  C = A[M,K] * B[N,K]^T
// bf16 in, fp32 accumulate, bf16/fp32 out.  2D batch (b,h) via grid.z (z = b*Hh + h).
template<int WM, int WN, bool OUTB>
__global__ __launch_bounds__(WM*WN*64) void gemm_bt(
    const u16* __restrict__ A, const u16* __restrict__ Bm, void* __restrict__ Cp,
    int K, int lda, int ldb, int ldc, int Hh,
    long aob, long aoh, long bob, long boh, long cob, long coh)
{
  constexpr int BM = WM*64, BN = WN*64, BK = 64, LSTR = BK + 8;
  __shared__ u16 At[BM*LSTR];
  __shared__ u16 Bt[BN*LSTR];
  int z = blockIdx.z, b_ = z / Hh, h_ = z % Hh;
  const u16* Ab = A + (long)b_*aob + (long)h_*aoh;
  const u16* Bb = Bm + (long)b_*bob + (long)h_*boh;
  long cbase = (long)b_*cob + (long)h_*coh;
  int m0 = blockIdx.y * BM, n0 = blockIdx.x * BN;
  int tid = threadIdx.x, lane = tid & 63, wv = tid >> 6;
  int wm = wv / WN, wn = wv % WN;
  constexpr int T = WM*WN*64;
  f32x4 acc[4][4];
  f32x4 z4 = {0.f, 0.f, 0.f, 0.f};
#pragma unroll
  for (int a = 0; a < 4; a++)
#pragma unroll
    for (int b = 0; b < 4; b++) acc[a][b] = z4;
  int lr = lane & 15, lk8 = (lane >> 4) * 8;
  for (int k0 = 0; k0 < K; k0 += BK){
    __syncthreads();
    for (int idx = tid; idx < BM*8; idx += T){
      int r = idx >> 3, c = (idx & 7) << 3;
      *(u16x8*)&At[r*LSTR + c] = *(const u16x8*)&Ab[(long)(m0 + r)*lda + k0 + c];
    }
    for (int idx = tid; idx < BN*8; idx += T){
      int r = idx >> 3, c = (idx & 7) << 3;
      *(u16x8*)&Bt[r*LSTR + c] = *(const u16x8*)&Bb[(long)(n0 + r)*ldb + k0 + c];
    }
    __syncthreads();
#pragma unroll
    for (int kk = 0; kk < BK; kk += 32){
      bf16x8 af[4], bfr[4];
#pragma unroll
      for (int mi = 0; mi < 4; mi++) af[mi]  = *(bf16x8*)&At[(wm*64 + mi*16 + lr)*LSTR + kk + lk8];
#pragma unroll
      for (int ni = 0; ni < 4; ni++) bfr[ni] = *(bf16x8*)&Bt[(wn*64 + ni*16 + lr)*LSTR + kk + lk8];
#pragma unroll
      for (int mi = 0; mi < 4; mi++)
#pragma unroll
        for (int ni = 0; ni < 4; ni++)
          acc[mi][ni] = __builtin_amdgcn_mfma_f32_16x16x32_bf16(af[mi], bfr[ni], acc[mi][ni], 0, 0, 0);
    }
  }
  int orow = (lane >> 4) * 4, ocol = lane & 15;
#pragma unroll
  for (int mi = 0; mi < 4; mi++)
#pragma unroll
    for (int ni = 0; ni < 4; ni++){
      int row = m0 + wm*64 + mi*16 + orow;
      int col = n0 + wn*64 + ni*16 + ocol;
      long cidx = cbase + (long)row*ldc + col;
#pragma unroll
      for (int r = 0; r < 4; r++){
        float vv = acc[mi][ni][r];
        if (OUTB) ((u16*)Cp)[cidx + (long)r*ldc] = f2b(vv);
        else      ((float*)Cp)[cidx + (long)r*ldc] = vv;
      }
    }
}

// ---------------------------------------------------------------- bf16 transpose dst[c,r]=src[r,c]
__global__ __launch_bounds__(256) void transpose_k(
    const u16* __restrict__ src, u16* __restrict__ dst,
    int lds_, int ldd, int Hh, long sob, long soh, long dob, long doh)
{
  __shared__ u16 tile[64*72];
  int z = blockIdx.z, b_ = z / Hh, h_ = z % Hh;
  const u16* S_ = src + (long)b_*sob + (long)h_*soh;
  u16* D_ = dst + (long)b_*dob + (long)h_*doh;
  int r0 = blockIdx.y * 64, c0 = blockIdx.x * 64;
  int tid = threadIdx.x;
  for (int idx = tid; idx < 512; idx += 256){
    int r = idx >> 3, c = (idx & 7) << 3;
    *(u16x8*)&tile[r*72 + c] = *(const u16x8*)&S_[(long)(r0 + r)*lds_ + c0 + c];
  }
  __syncthreads();
  for (int idx = tid; idx < 512; idx += 256){
    int c = idx >> 3, r = (idx & 7) << 3;
    u16x8 v;
#pragma unroll
    for (int e = 0; e < 8; e++) v[e] = tile[(r + e)*72 + c];
    *(u16x8*)&D_[(long)(c0 + c)*ldd + r0 + r] = v;
  }
}

// ---------------------------------------------------------------- fp32 src -> bf16 transposed dst
__global__ __launch_bounds__(256) void transpose_cvt_k(
    const float* __restrict__ src, u16* __restrict__ dst, int lds_, int ldd)
{
  __shared__ u16 tile[64*72];
  int r0 = blockIdx.y * 64, c0 = blockIdx.x * 64;
  int tid = threadIdx.x;
  for (int idx = tid; idx < 512; idx += 256){
    int r = idx >> 3, c = (idx & 7) << 3;
    const float* s = &src[(long)(r0 + r)*lds_ + c0 + c];
#pragma unroll
    for (int e = 0; e < 8; e++) tile[r*72 + c + e] = f2b(s[e]);
  }
  __syncthreads();
  for (int idx = tid; idx < 512; idx += 256){
    int c = idx >> 3, r = (idx & 7) << 3;
    u16x8 v;
#pragma unroll
    for (int e = 0; e < 8; e++) v[e] = tile[(r + e)*72 + c];
    *(u16x8*)&dst[(long)(c0 + c)*ldd + r0 + r] = v;
  }
}

// ---------------------------------------------------------------- flat fp32 -> bf16
__global__ __launch_bounds__(256) void cvt_k(const float* __restrict__ src, u16* __restrict__ dst)
{
  long i = ((long)blockIdx.x*256 + threadIdx.x) * 4;
  float4 v = *(const float4*)&src[i];
  u16x4 o; o[0] = f2b(v.x); o[1] = f2b(v.y); o[2] = f2b(v.z); o[3] = f2b(v.w);
  *(u16x4*)&dst[i] = o;
}

// ---------------------------------------------------------------- LayerNorm row=1024, fp32 in, bf16 out
__global__ __launch_bounds__(256) void ln_k(const float* __restrict__ src, const float* __restrict__ g,
                                            const float* __restrict__ be, u16* __restrict__ out)
{
  long base = (long)blockIdx.x * 1024;
  int tid = threadIdx.x;
  const float* s = src + base + tid*4;
  float v[4] = {s[0], s[1], s[2], s[3]};
  float s1 = v[0]+v[1]+v[2]+v[3];
  float s2 = v[0]*v[0]+v[1]*v[1]+v[2]*v[2]+v[3]*v[3];
  block_red2(s1, s2);
  float mu = s1 * (1.f/1024.f);
  float var = s2 * (1.f/1024.f) - mu*mu;
  float rs = rsqrtf(var + 1e-5f);
#pragma unroll
  for (int e = 0; e < 4; e++){
    int col = tid*4 + e;
    out[base + col] = f2b((v[e]-mu)*rs*g[col] + be[col]);
  }
}

// ---------------------------------------------------------------- out = resid + LN(go + xn + bias)  (fp32 out)
__global__ __launch_bounds__(256) void add_ln_k(const float* __restrict__ go, const u16* __restrict__ xn,
    const float* __restrict__ bias, const float* __restrict__ g, const float* __restrict__ be,
    const float* __restrict__ resid, float* __restrict__ outp)
{
  long base = (long)blockIdx.x * 1024;
  int tid = threadIdx.x;
  float v[4];
#pragma unroll
  for (int e = 0; e < 4; e++){
    int col = tid*4 + e;
    v[e] = go[base + col] + b2f(xn[base + col]) + bias[col];
  }
  float s1 = v[0]+v[1]+v[2]+v[3];
  float s2 = v[0]*v[0]+v[1]*v[1]+v[2]*v[2]+v[3]*v[3];
  block_red2(s1, s2);
  float mu = s1 * (1.f/1024.f);
  float var = s2 * (1.f/1024.f) - mu*mu;
  float rs = rsqrtf(var + 1e-5f);
#pragma unroll
  for (int e = 0; e < 4; e++){
    int col = tid*4 + e;
    outp[base + col] = resid[base + col] + (v[e]-mu)*rs*g[col] + be[col];
  }
}

// ---------------------------------------------------------------- QQ = [q+u | shifted(q+v)]  (B,S,H,128)
__global__ __launch_bounds__(256) void build_qq(const u16* __restrict__ q, const float* __restrict__ u,
                                                const float* __restrict__ v, u16* __restrict__ QQ)
{
  int bi = blockIdx.x;                       // bi = b*1024 + i
  long qrow = (long)bi * 1024;
  long obase = (long)bi * 2048;
  // rel_shift source: n = bi + B ; b'=n/(S+1) ; i'=n%(S+1) ; zero row if i'==0
  int n = bi + 2;
  int bp = n / 1025, ip = n % 1025;
  long qsrc = ip ? ((long)(bp*1024 + ip - 1)) * 1024 : -1;
  for (int t = threadIdx.x; t < 2048; t += 256){
    int h = t >> 7, e = t & 127;
    float val;
    if (e < 64) val = b2f(q[qrow + h*64 + e]) + u[h*64 + e];
    else {
      int d = e - 64;
      val = (qsrc < 0) ? 0.f : b2f(q[qsrc + h*64 + d]) + v[h*64 + d];
    }
    QQ[obase + t] = f2b(val);
  }
}

// ---------------------------------------------------------------- BB = [k | pos_emb]  (B,St,H,128)
__global__ __launch_bounds__(256) void build_bb(const u16* __restrict__ kv, const float* __restrict__ pe,
                                                u16* __restrict__ BB)
{
  int bj = blockIdx.x;                       // bj = b*2048 + j
  int j = bj & 2047;
  long kvrow = (long)bj * 2048;
  long obase = (long)bj * 2048;
  for (int t = threadIdx.x; t < 2048; t += 256){
    int h = t >> 7, e = t & 127;
    u16 val = (e < 64) ? kv[kvrow + h*64 + e] : f2b(pe[(long)j*1024 + h*64 + (e - 64)]);
    BB[obase + t] = val;
  }
}

// ---------------------------------------------------------------- row softmax on scT (rows contiguous, len 1024)
// one wave per row; row gr -> head h'=gr/JR, ctx j=gr%JR; softmax over i (contiguous);
// mask (MHA): valid i >= j - Mctx  -> prefix zeros
__global__ __launch_bounds__(256) void softmax_row(u16* __restrict__ sc, int JR, int Mctx,
                                                   int maskon, float scale)
{
  int gr = blockIdx.x*4 + (threadIdx.x >> 6);
  int lane = threadIdx.x & 63;
  int j = gr & (JR - 1);
  u16* p = sc + (long)gr * 1024;
  int i0 = 0;
  if (maskon){ i0 = j - Mctx; if (i0 < 0) i0 = 0; }
  u16x8 v0 = *(const u16x8*)&p[lane*16];
  u16x8 v1 = *(const u16x8*)&p[lane*16 + 8];
  float x[16];
#pragma unroll
  for (int e = 0; e < 8; e++){ x[e] = b2f(v0[e]); x[8+e] = b2f(v1[e]); }
  int ibase = lane*16;
  float m = -3.0e38f;
#pragma unroll
  for (int e = 0; e < 16; e++){
    x[e] = (ibase + e < i0) ? -3.0e38f : x[e]*scale;
    m = fmaxf(m, x[e]);
  }
#pragma unroll
  for (int off = 32; off; off >>= 1) m = fmaxf(m, __shfl_xor(m, off));
  float y[16];
  float s = 0.f;
#pragma unroll
  for (int e = 0; e < 16; e++){ y[e] = __expf(x[e] - m); s += y[e]; }
#pragma unroll
  for (int off = 32; off; off >>= 1) s += __shfl_xor(s, off);
  float inv = 1.f / s;
  u16x8 o0, o1;
#pragma unroll
  for (int e = 0; e < 8; e++){ o0[e] = f2b(y[e]*inv); o1[e] = f2b(y[8+e]*inv); }
  *(u16x8*)&p[lane*16] = o0;
  *(u16x8*)&p[lane*16 + 8] = o1;
}

// ---------------------------------------------------------------- gelu(exact) + bias, fp32 in, bf16 out
__global__ __launch_bounds__(256) void gelu_k(const float* __restrict__ f1, const float* __restrict__ b1,
                                              u16* __restrict__ h1)
{
  long i = (long)blockIdx.x*256 + threadIdx.x;
  float x = f1[i] + b1[i & 4095];
  h1[i] = f2b(0.5f * x * (1.f + erff(x * 0.70710678118654752f)));
}

// ---------------------------------------------------------------- out3 = out2 + f2 + b2  (fp32 out)
__global__ __launch_bounds__(256) void final_k(const float* __restrict__ out2, const float* __restrict__ f2,
                                               const float* __restrict__ b2v, float* __restrict__ outp)
{
  long i = (long)blockIdx.x*256 + threadIdx.x;
  outp[i] = out2[i] + f2[i] + b2v[i & 1023];
}

// ================================================================ host
extern "C" void kernel_launch(void* const* d_in, const int* in_sizes, int n_in,
                              void* d_out, int out_size, void* d_ws, size_t ws_size,
                              hipStream_t stream)
{
  (void)in_sizes; (void)n_in; (void)out_size; (void)ws_size;
  // B=2 S=1024 M=1024 St=2048 D=DI=1024 H=16 DH=64 DFF=4096 ; ALL inputs/output fp32
  const float* X    = (const float*)d_in[0];
  const float* ENC  = (const float*)d_in[1];
  const float* PE   = (const float*)d_in[2];
  const float* Uu   = (const float*)d_in[3];
  const float* Vv   = (const float*)d_in[4];
  const float* MEM  = (const float*)d_in[5];
  const float* WQM  = (const float*)d_in[7];
  const float* WKVM = (const float*)d_in[8];
  const float* FCWM = (const float*)d_in[9];
  const float* FCBM = (const float*)d_in[10];
  const float* LNMG = (const float*)d_in[11];
  const float* LNMB = (const float*)d_in[12];
  const float* WQC  = (const float*)d_in[13];
  const float* WKVC = (const float*)d_in[14];
  const float* FCWC = (const float*)d_in[15];
  const float* FCBC = (const float*)d_in[16];
  const float* LNCG = (const float*)d_in[17];
  const float* LNCB = (const float*)d_in[18];
  const float* W1   = (const float*)d_in[19];
  const float* B1   = (const float*)d_in[20];
  const float* W2   = (const float*)d_in[21];
  const float* B2   = (const float*)d_in[22];
  const float* LN1G = (const float*)d_in[23];
  const float* LN1B = (const float*)d_in[24];
  const float* LN2G = (const float*)d_in[25];
  const float* LN2B = (const float*)d_in[26];
  const float* LN3G = (const float*)d_in[27];
  const float* LN3B = (const float*)d_in[28];
  float* OUT = (float*)d_out;
  char* W = (char*)d_ws;
  const size_t MB = 1ull << 20;

  // ---- lifetime-overlapped layout, peak 120 MB
  // [0,8)    rotating weight region (bf16): MHA wq/wkv/fcw -> cross wq/wkv/fcw -> w1T
  // [8,12)   xn1
  // [12,16)  q -> o_b
  // [16,32)  kv -> ofc [16,24) + outb [24,32)
  // [32,40)  QQ -> xn2 [32,36) + qc [36,40)
  // [40,56)  BB -> kvc [40,48) + Vtc [48,52) + oc [52,56)
  // [56,64)  Vt -> w2T
  // [64,80)  memb/encb [64,68) ; scT 16MB ; f1 [64,96) -> f2 [64,72)
  // [80,96)  Pbuf 16MB ; (f1 upper half later)
  // [96,112) h1
  // [112,120) out2b (fp32)
  u16*   wT_a  = (u16*)(W + 0*MB);
  u16*   wT_b  = (u16*)(W + 2*MB);
  u16*   wT_c  = (u16*)(W + 6*MB);
  u16*   w1T   = (u16*)(W + 0*MB);
  u16*   xn1   = (u16*)(W + 8*MB);
  u16*   q     = (u16*)(W + 12*MB);
  u16*   o_b   = (u16*)(W + 12*MB);
  u16*   kv    = (u16*)(W + 16*MB);
  float* ofc   = (float*)(W + 16*MB);
  float* outb  = (float*)(W + 24*MB);
  u16*   QQ    = (u16*)(W + 32*MB);
  u16*   xn2   = (u16*)(W + 32*MB);
  u16*   qc    = (u16*)(W + 36*MB);
  u16*   BB    = (u16*)(W + 40*MB);
  u16*   kvc   = (u16*)(W + 40*MB);
  u16*   Vtc   = (u16*)(W + 48*MB);
  u16*   oc    = (u16*)(W + 52*MB);
  u16*   Vt    = (u16*)(W + 56*MB);
  u16*   w2T   = (u16*)(W + 56*MB);
  u16*   memb  = (u16*)(W + 64*MB);
  u16*   encb  = (u16*)(W + 64*MB);
  u16*   scT   = (u16*)(W + 64*MB);
  u16*   Pbuf  = (u16*)(W + 80*MB);
  float* f1    = (float*)(W + 64*MB);
  float* f2    = (float*)(W + 64*MB);
  u16*   h1    = (u16*)(W + 96*MB);
  float* out2b = (float*)(W + 112*MB);

  // ================= MHA (Transformer-XL relative attention) =================
  transpose_cvt_k<<<dim3(16,16),256,0,stream>>>(WQM,  wT_a, 1024,1024);
  transpose_cvt_k<<<dim3(32,16),256,0,stream>>>(WKVM, wT_b, 2048,1024);
  transpose_cvt_k<<<dim3(16,16),256,0,stream>>>(FCWM, wT_c, 1024,1024);
  cvt_k<<<2048,256,0,stream>>>(MEM, memb);       // 2M elems
  ln_k<<<2048,256,0,stream>>>(X, LN1G, LN1B, xn1);
  gemm_bt<2,2,true><<<dim3(8,16,1),256,0,stream>>>(xn1, wT_a, q, 1024, 1024,1024,1024, 1, 0,0,0,0,0,0);
  // kv = [mem ; xn1] @ Wkv_m  (rows 0..1023 = mem, 1024..2047 = xn1, per b)
  gemm_bt<2,2,true><<<dim3(16,8,2),256,0,stream>>>(memb, wT_b, kv, 1024, 1024,1024,2048, 1,
      1048576,0, 0,0, 4194304,0);
  gemm_bt<2,2,true><<<dim3(16,8,2),256,0,stream>>>(xn1, wT_b, kv + (size_t)1024*2048, 1024, 1024,1024,2048, 1,
      1048576,0, 0,0, 4194304,0);
  build_qq<<<2048,256,0,stream>>>(q, Uu, Vv, QQ);
  build_bb<<<4096,256,0,stream>>>(kv, PE, BB);
  transpose_k<<<dim3(1,32,32),256,0,stream>>>(kv + 1024, Vt, 2048, 2048, 16,
      4194304,64, 2097152,131072);
  // per (b, 4-head chunk): scT = BB@QQ^T (transposed scores) ; row-softmax ; P = scT^T ; o = P@Vt^T
  for (int b = 0; b < 2; b++)
    for (int c = 0; c < 4; c++){
      gemm_bt<2,2,true><<<dim3(8,16,4),256,0,stream>>>(
          BB + (size_t)b*4194304 + c*512, QQ + (size_t)b*2097152 + c*512, scT,
          128, 2048,2048,1024, 4, 0,128, 0,128, 0,2097152);
      softmax_row<<<2048,256,0,stream>>>(scT, 2048, 1024, 1, 0.125f);
      transpose_k<<<dim3(16,32,4),256,0,stream>>>(scT, Pbuf, 1024, 2048, 4, 0,2097152, 0,2097152);
      gemm_bt<2,1,true><<<dim3(1,8,4),128,0,stream>>>(
          Pbuf, Vt + (size_t)b*2097152 + (size_t)c*4*131072, o_b + (size_t)b*1048576 + c*256,
          2048, 2048,2048,1024, 4, 0,2097152, 0,131072, 0,64);
    }
  gemm_bt<2,2,false><<<dim3(8,16,1),256,0,stream>>>(o_b, wT_c, ofc, 1024, 1024,1024,1024, 1, 0,0,0,0,0,0);
  add_ln_k<<<2048,256,0,stream>>>(ofc, xn1, FCBM, LNMG, LNMB, X, outb);

  // ================= cross attention =================
  transpose_cvt_k<<<dim3(16,16),256,0,stream>>>(WQC,  wT_a, 1024,1024);
  transpose_cvt_k<<<dim3(32,16),256,0,stream>>>(WKVC, wT_b, 2048,1024);
  transpose_cvt_k<<<dim3(16,16),256,0,stream>>>(FCWC, wT_c, 1024,1024);
  cvt_k<<<2048,256,0,stream>>>(ENC, encb);       // 2M elems
  ln_k<<<2048,256,0,stream>>>(outb, LN2G, LN2B, xn2);
  gemm_bt<2,2,true><<<dim3(8,16,1),256,0,stream>>>(xn2, wT_a, qc, 1024, 1024,1024,1024, 1, 0,0,0,0,0,0);
  gemm_bt<2,2,true><<<dim3(16,16,1),256,0,stream>>>(encb, wT_b, kvc, 1024, 1024,1024,2048, 1, 0,0,0,0,0,0);
  transpose_k<<<dim3(1,16,32),256,0,stream>>>(kvc + 1024, Vtc, 2048, 1024, 16,
      2097152,64, 1048576,65536);
  // per (b, 8-head chunk)
  for (int b = 0; b < 2; b++)
    for (int hc = 0; hc < 2; hc++){
      gemm_bt<2,2,true><<<dim3(8,8,8),256,0,stream>>>(
          kvc + (size_t)b*2097152 + hc*512, qc + (size_t)b*1048576 + hc*512, scT,
          64, 2048,1024,1024, 8, 0,64, 0,64, 0,1048576);
      softmax_row<<<2048,256,0,stream>>>(scT, 1024, 0, 0, 0.125f);
      transpose_k<<<dim3(16,16,8),256,0,stream>>>(scT, Pbuf, 1024, 1024, 8, 0,1048576, 0,1048576);
      gemm_bt<2,1,true><<<dim3(1,8,8),128,0,stream>>>(
          Pbuf, Vtc + (size_t)b*1048576 + (size_t)hc*8*65536, oc + (size_t)b*1048576 + hc*512,
          1024, 1024,1024,1024, 8, 0,1048576, 0,65536, 0,64);
    }
  gemm_bt<2,2,false><<<dim3(8,16,1),256,0,stream>>>(oc, wT_c, ofc, 1024, 1024,1024,1024, 1, 0,0,0,0,0,0);
  add_ln_k<<<2048,256,0,stream>>>(ofc, xn2, FCBC, LNCG, LNCB, outb, out2b);

  // ================= FFN =================
  transpose_cvt_k<<<dim3(64,16),256,0,stream>>>(W1, w1T, 4096,1024);
  transpose_cvt_k<<<dim3(16,64),256,0,stream>>>(W2, w2T, 1024,4096);
  ln_k<<<2048,256,0,stream>>>(out2b, LN3G, LN3B, xn2);   // xn3 reuses xn2 slot
  gemm_bt<2,2,false><<<dim3(32,16,1),256,0,stream>>>(xn2, w1T, f1, 1024, 1024,1024,4096, 1, 0,0,0,0,0,0);
  gelu_k<<<32768,256,0,stream>>>(f1, B1, h1);
  gemm_bt<2,2,false><<<dim3(8,16,1),256,0,stream>>>(h1, w2T, f2, 4096, 4096,4096,1024, 1, 0,0,0,0,0,0);
  final_k<<<8192,256,0,stream>>>(out2b, f2, B2, OUT);
}

// Round 6
// 1111.157 us; speedup vs baseline: 4.7004x; 2.3967x over previous
//
#include <hip/hip_runtime.h>

typedef unsigned short u16;
typedef __attribute__((ext_vector_type(4))) unsigned short u16x4;
typedef __attribute__((ext_vector_type(8))) unsigned short u16x8;
typedef __attribute__((ext_vector_type(8))) __bf16 bf16x8;
typedef __attribute__((ext_vector_type(4))) float f32x4;

#define DEV __device__ __forceinline__

DEV float b2f(u16 u){ union{ unsigned int i; float f; } x; x.i = ((unsigned int)u) << 16; return x.f; }
DEV u16 f2b(float f){ unsigned int x = __float_as_uint(f); return (u16)((x + 0x7fffu + ((x >> 16) & 1u)) >> 16); }

// ---------------------------------------------------------------- block reduce (256 thr)
DEV void block_red2(float& s, float& q){
#pragma unroll
  for (int off = 32; off; off >>= 1){ s += __shfl_down(s, off); q += __shfl_down(q, off); }
  __shared__ float sh1[4], sh2[4];
  int lane = threadIdx.x & 63, w = threadIdx.x >> 6;
  if (lane == 0){ sh1[w] = s; sh2[w] = q; }
  __syncthreads();
  s = sh1[0] + sh1[1] + sh1[2] + sh1[3];
  q = sh2[0] + sh2[1] + sh2[2] + sh2[3];
}

// ---------------------------------------------------------------- GEMM  C = A[M,K] * B[N,K]^T
// bf16 in, fp32 accumulate, bf16/fp32 out.  2D batch (b,h) via grid.z (z = b*Hh + h).
template<int WM, int WN, bool OUTB>
__global__ __launch_bounds__(WM*WN*64) void gemm_bt(
    const u16* __restrict__ A, const u16* __restrict__ Bm, void* __restrict__ Cp,
    int K, int lda, int ldb, int ldc, int Hh,
    long aob, long aoh, long bob, long boh, long cob, long coh)
{
  constexpr int BM = WM*64, BN = WN*64, BK = 64, LSTR = BK + 8;
  __shared__ u16 At[BM*LSTR];
  __shared__ u16 Bt[BN*LSTR];
  int z = blockIdx.z, b_ = z / Hh, h_ = z % Hh;
  const u16* Ab = A + (long)b_*aob + (long)h_*aoh;
  const u16* Bb = Bm + (long)b_*bob + (long)h_*boh;
  long cbase = (long)b_*cob + (long)h_*coh;
  int m0 = blockIdx.y * BM, n0 = blockIdx.x * BN;
  int tid = threadIdx.x, lane = tid & 63, wv = tid >> 6;
  int wm = wv / WN, wn = wv % WN;
  constexpr int T = WM*WN*64;
  f32x4 acc[4][4];
  f32x4 z4 = {0.f, 0.f, 0.f, 0.f};
#pragma unroll
  for (int a = 0; a < 4; a++)
#pragma unroll
    for (int b = 0; b < 4; b++) acc[a][b] = z4;
  int lr = lane & 15, lk8 = (lane >> 4) * 8;
  for (int k0 = 0; k0 < K; k0 += BK){
    __syncthreads();
    for (int idx = tid; idx < BM*8; idx += T){
      int r = idx >> 3, c = (idx & 7) << 3;
      *(u16x8*)&At[r*LSTR + c] = *(const u16x8*)&Ab[(long)(m0 + r)*lda + k0 + c];
    }
    for (int idx = tid; idx < BN*8; idx += T){
      int r = idx >> 3, c = (idx & 7) << 3;
      *(u16x8*)&Bt[r*LSTR + c] = *(const u16x8*)&Bb[(long)(n0 + r)*ldb + k0 + c];
    }
    __syncthreads();
#pragma unroll
    for (int kk = 0; kk < BK; kk += 32){
      bf16x8 af[4], bfr[4];
#pragma unroll
      for (int mi = 0; mi < 4; mi++) af[mi]  = *(bf16x8*)&At[(wm*64 + mi*16 + lr)*LSTR + kk + lk8];
#pragma unroll
      for (int ni = 0; ni < 4; ni++) bfr[ni] = *(bf16x8*)&Bt[(wn*64 + ni*16 + lr)*LSTR + kk + lk8];
#pragma unroll
      for (int mi = 0; mi < 4; mi++)
#pragma unroll
        for (int ni = 0; ni < 4; ni++)
          acc[mi][ni] = __builtin_amdgcn_mfma_f32_16x16x32_bf16(af[mi], bfr[ni], acc[mi][ni], 0, 0, 0);
    }
  }
  int orow = (lane >> 4) * 4, ocol = lane & 15;
#pragma unroll
  for (int mi = 0; mi < 4; mi++)
#pragma unroll
    for (int ni = 0; ni < 4; ni++){
      int row = m0 + wm*64 + mi*16 + orow;
      int col = n0 + wn*64 + ni*16 + ocol;
      long cidx = cbase + (long)row*ldc + col;
#pragma unroll
      for (int r = 0; r < 4; r++){
        float vv = acc[mi][ni][r];
        if (OUTB) ((u16*)Cp)[cidx + (long)r*ldc] = f2b(vv);
        else      ((float*)Cp)[cidx + (long)r*ldc] = vv;
      }
    }
}

// ---------------------------------------------------------------- fused attention, query-axis softmax
// Pass A: per (b,h,j-tile): m_j = max_i s_ij*scale (masked), Z_j = sum_i exp(.-m_j); writes m, 1/Z.
// S computed via MFMA: A=K rows (j), B=Q rows (i), K-dim = KD (contig per head).
template<int KD, bool MASK>
__global__ __launch_bounds__(256) void attn_passA(
    const u16* __restrict__ Kp, const u16* __restrict__ Qp, float* __restrict__ mz,
    int J, int kld, int qld,
    long kob, long koh, long qob, long qoh, int H, float scale, int mztot)
{
  __shared__ u16 Kt[128*KD];
  __shared__ u16 Qt[128*KD];
  int bh = blockIdx.y, b = bh / H, h = bh % H;
  const u16* Kb = Kp + (long)b*kob + (long)h*koh;
  const u16* Qb = Qp + (long)b*qob + (long)h*qoh;
  int j0 = blockIdx.x * 128;
  int tid = threadIdx.x, lane = tid & 63, w = tid >> 6;
  int lr = lane & 15, lk8 = (lane >> 4) * 8;
  constexpr int RCH = KD / 8;
  for (int idx = tid; idx < 128*RCH; idx += 256){
    int r = idx / RCH, c = (idx % RCH) * 8;
    *(u16x8*)&Kt[r*KD + c] = *(const u16x8*)&Kb[(long)(j0 + r)*kld + c];
  }
  float m_run[2][4], z_run[2][4];
#pragma unroll
  for (int mi = 0; mi < 2; mi++)
#pragma unroll
    for (int r = 0; r < 4; r++){ m_run[mi][r] = -3.0e38f; z_run[mi][r] = 0.f; }
  for (int it = 0; it < 8; it++){
    if (MASK && (it*128 + 127 < j0 - 1024)) continue;   // whole i-tile masked for all rows
    __syncthreads();
    for (int idx = tid; idx < 128*RCH; idx += 256){
      int r = idx / RCH, c = (idx % RCH) * 8;
      *(u16x8*)&Qt[r*KD + c] = *(const u16x8*)&Qb[(long)(it*128 + r)*qld + c];
    }
    __syncthreads();
    f32x4 acc[2][8];
    f32x4 zz = {0.f,0.f,0.f,0.f};
#pragma unroll
    for (int mi = 0; mi < 2; mi++)
#pragma unroll
      for (int ni = 0; ni < 8; ni++) acc[mi][ni] = zz;
#pragma unroll
    for (int kk = 0; kk < KD; kk += 32){
      bf16x8 af[2], bq[8];
#pragma unroll
      for (int mi = 0; mi < 2; mi++) af[mi] = *(bf16x8*)&Kt[(w*32 + mi*16 + lr)*KD + kk + lk8];
#pragma unroll
      for (int ni = 0; ni < 8; ni++) bq[ni] = *(bf16x8*)&Qt[(ni*16 + lr)*KD + kk + lk8];
#pragma unroll
      for (int mi = 0; mi < 2; mi++)
#pragma unroll
        for (int ni = 0; ni < 8; ni++)
          acc[mi][ni] = __builtin_amdgcn_mfma_f32_16x16x32_bf16(af[mi], bq[ni], acc[mi][ni], 0, 0, 0);
    }
#pragma unroll
    for (int mi = 0; mi < 2; mi++)
#pragma unroll
      for (int r = 0; r < 4; r++){
        int jg = j0 + w*32 + mi*16 + ((lane >> 4) << 2) + r;
        float sv[8]; float tm = -3.0e38f;
#pragma unroll
        for (int ni = 0; ni < 8; ni++){
          int ig = it*128 + ni*16 + (lane & 15);
          float s = acc[mi][ni][r] * scale;
          bool val = (!MASK) || (ig >= jg - 1024);
          sv[ni] = val ? s : -3.0e38f;
          tm = fmaxf(tm, sv[ni]);
        }
#pragma unroll
        for (int off = 1; off < 16; off <<= 1) tm = fmaxf(tm, __shfl_xor(tm, off));
        float mn = fmaxf(m_run[mi][r], tm);
        float zt = 0.f;
#pragma unroll
        for (int ni = 0; ni < 8; ni++)
          zt += (sv[ni] > -1.0e37f) ? __expf(sv[ni] - mn) : 0.f;
#pragma unroll
        for (int off = 1; off < 16; off <<= 1) zt += __shfl_xor(zt, off);
        z_run[mi][r] = z_run[mi][r] * __expf(m_run[mi][r] - mn) + zt;
        m_run[mi][r] = mn;
      }
  }
  if ((lane & 15) == 0){
#pragma unroll
    for (int mi = 0; mi < 2; mi++)
#pragma unroll
      for (int r = 0; r < 4; r++){
        int jg = j0 + w*32 + mi*16 + ((lane >> 4) << 2) + r;
        mz[(long)bh*J + jg] = m_run[mi][r];
        mz[(long)mztot + (long)bh*J + jg] = 1.f / z_run[mi][r];
      }
  }
}

// Pass B: per (b,h,i-tile): o[i,d] = sum_j exp(s_ij*scale - m_j)/Z_j * V[j,d].
// S recomputed; P round-trips through LDS (C-layout -> A-layout); PV via MFMA with Vt[d,j].
template<int KD, bool MASK>
__global__ __launch_bounds__(256) void attn_passB(
    const u16* __restrict__ Kp, const u16* __restrict__ Qp, const u16* __restrict__ Vtp,
    const float* __restrict__ mz, u16* __restrict__ Op,
    int J, int kld, int qld, int vld, int oldd,
    long kob, long koh, long qob, long qoh, long vob, long voh, long oob, long ooh,
    int H, float scale, int mztot)
{
  __shared__ u16 Qt[128*KD];
  __shared__ u16 PK[128*128];                      // P tile; doubles as K tile when KD==128
  __shared__ u16 KtSep[(KD==128) ? 2 : 128*KD];    // separate K tile for KD<128
  __shared__ u16 Vtt[64*128];
  u16* Kt = (KD == 128) ? PK : KtSep;
  u16* Pt = PK;
  int bh = blockIdx.y, b = bh / H, h = bh % H;
  const u16* Kb = Kp + (long)b*kob + (long)h*koh;
  const u16* Qb = Qp + (long)b*qob + (long)h*qoh;
  const u16* Vb = Vtp + (long)b*vob + (long)h*voh;
  u16* Ob = Op + (long)b*oob + (long)h*ooh;
  const float* mzm = mz + (long)bh*J;
  const float* mzz = mz + (long)mztot + (long)bh*J;
  int i0 = blockIdx.x * 128;
  int tid = threadIdx.x, lane = tid & 63, w = tid >> 6;
  int lr = lane & 15, lk8 = (lane >> 4) * 8;
  constexpr int RCH = KD / 8;
  // stage Q i-tile once
  for (int idx = tid; idx < 128*RCH; idx += 256){
    int r = idx / RCH, c = (idx % RCH) * 8;
    *(u16x8*)&Qt[r*KD + c] = *(const u16x8*)&Qb[(long)(i0 + r)*qld + c];
  }
  f32x4 acc_o[2][4];
  f32x4 zz = {0.f,0.f,0.f,0.f};
#pragma unroll
  for (int mi = 0; mi < 2; mi++)
#pragma unroll
    for (int nd = 0; nd < 4; nd++) acc_o[mi][nd] = zz;
  int JT = J >> 7;
  for (int jt = 0; jt < JT; jt++){
    if (MASK && (jt*128 > i0 + 1151)) continue;    // whole j-tile masked for all i in tile
    __syncthreads();                               // prev iter's P/Vt reads done
    for (int idx = tid; idx < 128*RCH; idx += 256){
      int r = idx / RCH, c = (idx % RCH) * 8;
      *(u16x8*)&Kt[r*KD + c] = *(const u16x8*)&Kb[(long)(jt*128 + r)*kld + c];
    }
    for (int idx = tid; idx < 64*16; idx += 256){
      int r = idx >> 4, c = (idx & 15) << 3;
      *(u16x8*)&Vtt[r*128 + c] = *(const u16x8*)&Vb[(long)r*vld + jt*128 + c];
    }
    __syncthreads();
    // S tile: A = Q (rows i, own wave's 32), B = K (all 128 j)
    f32x4 acc[2][8];
#pragma unroll
    for (int mi = 0; mi < 2; mi++)
#pragma unroll
      for (int ni = 0; ni < 8; ni++) acc[mi][ni] = zz;
#pragma unroll
    for (int kk = 0; kk < KD; kk += 32){
      bf16x8 aq[2], bk[8];
#pragma unroll
      for (int mi = 0; mi < 2; mi++) aq[mi] = *(bf16x8*)&Qt[(w*32 + mi*16 + lr)*KD + kk + lk8];
#pragma unroll
      for (int ni = 0; ni < 8; ni++) bk[ni] = *(bf16x8*)&Kt[(ni*16 + lr)*KD + kk + lk8];
#pragma unroll
      for (int mi = 0; mi < 2; mi++)
#pragma unroll
        for (int ni = 0; ni < 8; ni++)
          acc[mi][ni] = __builtin_amdgcn_mfma_f32_16x16x32_bf16(aq[mi], bk[ni], acc[mi][ni], 0, 0, 0);
    }
    __syncthreads();                               // all K reads done before P overwrite (alias)
    // p = exp(s*scale - m_j) * zinv_j  (masked -> 0), write P in [i][j] layout
#pragma unroll
    for (int ni = 0; ni < 8; ni++){
      int jg = jt*128 + ni*16 + (lane & 15);
      float mj = mzm[jg], zj = mzz[jg];
#pragma unroll
      for (int mi = 0; mi < 2; mi++)
#pragma unroll
        for (int r = 0; r < 4; r++){
          int ig = i0 + w*32 + mi*16 + ((lane >> 4) << 2) + r;
          bool val = (!MASK) || (ig >= jg - 1024);
          float p = val ? __expf(acc[mi][ni][r] * scale - mj) * zj : 0.f;
          Pt[(w*32 + mi*16 + ((lane >> 4) << 2) + r)*128 + ni*16 + (lane & 15)] = f2b(p);
        }
    }
    __syncthreads();                               // P visible (own-wave reads, but keep safe)
    // PV: A = P (own wave's i rows), B = Vt (d rows)
#pragma unroll
    for (int kk = 0; kk < 128; kk += 32){
      bf16x8 pa[2], vb[4];
#pragma unroll
      for (int mi = 0; mi < 2; mi++) pa[mi] = *(bf16x8*)&Pt[(w*32 + mi*16 + lr)*128 + kk + lk8];
#pragma unroll
      for (int nd = 0; nd < 4; nd++) vb[nd] = *(bf16x8*)&Vtt[(nd*16 + lr)*128 + kk + lk8];
#pragma unroll
      for (int mi = 0; mi < 2; mi++)
#pragma unroll
        for (int nd = 0; nd < 4; nd++)
          acc_o[mi][nd] = __builtin_amdgcn_mfma_f32_16x16x32_bf16(pa[mi], vb[nd], acc_o[mi][nd], 0, 0, 0);
    }
  }
#pragma unroll
  for (int mi = 0; mi < 2; mi++)
#pragma unroll
    for (int nd = 0; nd < 4; nd++)
#pragma unroll
      for (int r = 0; r < 4; r++){
        int ig = i0 + w*32 + mi*16 + ((lane >> 4) << 2) + r;
        int d = nd*16 + (lane & 15);
        Ob[(long)ig*oldd + d] = f2b(acc_o[mi][nd][r]);
      }
}

// ---------------------------------------------------------------- bf16 transpose dst[c,r]=src[r,c]
__global__ __launch_bounds__(256) void transpose_k(
    const u16* __restrict__ src, u16* __restrict__ dst,
    int lds_, int ldd, int Hh, long sob, long soh, long dob, long doh)
{
  __shared__ u16 tile[64*72];
  int z = blockIdx.z, b_ = z / Hh, h_ = z % Hh;
  const u16* S_ = src + (long)b_*sob + (long)h_*soh;
  u16* D_ = dst + (long)b_*dob + (long)h_*doh;
  int r0 = blockIdx.y * 64, c0 = blockIdx.x * 64;
  int tid = threadIdx.x;
  for (int idx = tid; idx < 512; idx += 256){
    int r = idx >> 3, c = (idx & 7) << 3;
    *(u16x8*)&tile[r*72 + c] = *(const u16x8*)&S_[(long)(r0 + r)*lds_ + c0 + c];
  }
  __syncthreads();
  for (int idx = tid; idx < 512; idx += 256){
    int c = idx >> 3, r = (idx & 7) << 3;
    u16x8 v;
#pragma unroll
    for (int e = 0; e < 8; e++) v[e] = tile[(r + e)*72 + c];
    *(u16x8*)&D_[(long)(c0 + c)*ldd + r0 + r] = v;
  }
}

// ---------------------------------------------------------------- fp32 src -> bf16 transposed dst
__global__ __launch_bounds__(256) void transpose_cvt_k(
    const float* __restrict__ src, u16* __restrict__ dst, int lds_, int ldd)
{
  __shared__ u16 tile[64*72];
  int r0 = blockIdx.y * 64, c0 = blockIdx.x * 64;
  int tid = threadIdx.x;
  for (int idx = tid; idx < 512; idx += 256){
    int r = idx >> 3, c = (idx & 7) << 3;
    const float* s = &src[(long)(r0 + r)*lds_ + c0 + c];
#pragma unroll
    for (int e = 0; e < 8; e++) tile[r*72 + c + e] = f2b(s[e]);
  }
  __syncthreads();
  for (int idx = tid; idx < 512; idx += 256){
    int c = idx >> 3, r = (idx & 7) << 3;
    u16x8 v;
#pragma unroll
    for (int e = 0; e < 8; e++) v[e] = tile[(r + e)*72 + c];
    *(u16x8*)&dst[(long)(c0 + c)*ldd + r0 + r] = v;
  }
}

// ---------------------------------------------------------------- flat fp32 -> bf16
__global__ __launch_bounds__(256) void cvt_k(const float* __restrict__ src, u16* __restrict__ dst)
{
  long i = ((long)blockIdx.x*256 + threadIdx.x) * 4;
  float4 v = *(const float4*)&src[i];
  u16x4 o; o[0] = f2b(v.x); o[1] = f2b(v.y); o[2] = f2b(v.z); o[3] = f2b(v.w);
  *(u16x4*)&dst[i] = o;
}

// ---------------------------------------------------------------- LayerNorm row=1024, fp32 in, bf16 out
__global__ __launch_bounds__(256) void ln_k(const float* __restrict__ src, const float* __restrict__ g,
                                            const float* __restrict__ be, u16* __restrict__ out)
{
  long base = (long)blockIdx.x * 1024;
  int tid = threadIdx.x;
  const float* s = src + base + tid*4;
  float v[4] = {s[0], s[1], s[2], s[3]};
  float s1 = v[0]+v[1]+v[2]+v[3];
  float s2 = v[0]*v[0]+v[1]*v[1]+v[2]*v[2]+v[3]*v[3];
  block_red2(s1, s2);
  float mu = s1 * (1.f/1024.f);
  float var = s2 * (1.f/1024.f) - mu*mu;
  float rs = rsqrtf(var + 1e-5f);
#pragma unroll
  for (int e = 0; e < 4; e++){
    int col = tid*4 + e;
    out[base + col] = f2b((v[e]-mu)*rs*g[col] + be[col]);
  }
}

// ---------------------------------------------------------------- out = resid + LN(go1 + go2 + xn + bias)  (fp32 out)
__global__ __launch_bounds__(256) void add_ln_k(const float* __restrict__ go1, const float* __restrict__ go2,
    const u16* __restrict__ xn, const float* __restrict__ bias,
    const float* __restrict__ g, const float* __restrict__ be,
    const float* __restrict__ resid, float* __restrict__ outp)
{
  long base = (long)blockIdx.x * 1024;
  int tid = threadIdx.x;
  float v[4];
#pragma unroll
  for (int e = 0; e < 4; e++){
    int col = tid*4 + e;
    v[e] = go1[base + col] + go2[base + col] + b2f(xn[base + col]) + bias[col];
  }
  float s1 = v[0]+v[1]+v[2]+v[3];
  float s2 = v[0]*v[0]+v[1]*v[1]+v[2]*v[2]+v[3]*v[3];
  block_red2(s1, s2);
  float mu = s1 * (1.f/1024.f);
  float var = s2 * (1.f/1024.f) - mu*mu;
  float rs = rsqrtf(var + 1e-5f);
#pragma unroll
  for (int e = 0; e < 4; e++){
    int col = tid*4 + e;
    outp[base + col] = resid[base + col] + (v[e]-mu)*rs*g[col] + be[col];
  }
}

// ---------------------------------------------------------------- QQ = [q+u | shifted(q+v)]  (B,S,H,128)
__global__ __launch_bounds__(256) void build_qq(const u16* __restrict__ q, const float* __restrict__ u,
                                                const float* __restrict__ v, u16* __restrict__ QQ)
{
  int bi = blockIdx.x;                       // bi = b*1024 + i
  long qrow = (long)bi * 1024;
  long obase = (long)bi * 2048;
  int n = bi + 2;
  int bp = n / 1025, ip = n % 1025;
  long qsrc = ip ? ((long)(bp*1024 + ip - 1)) * 1024 : -1;
  for (int t = threadIdx.x; t < 2048; t += 256){
    int h = t >> 7, e = t & 127;
    float val;
    if (e < 64) val = b2f(q[qrow + h*64 + e]) + u[h*64 + e];
    else {
      int d = e - 64;
      val = (qsrc < 0) ? 0.f : b2f(q[qsrc + h*64 + d]) + v[h*64 + d];
    }
    QQ[obase + t] = f2b(val);
  }
}

// ---------------------------------------------------------------- BB = [k | pos_emb]  (B,St,H,128)
__global__ __launch_bounds__(256) void build_bb(const u16* __restrict__ kv, const float* __restrict__ pe,
                                                u16* __restrict__ BB)
{
  int bj = blockIdx.x;                       // bj = b*2048 + j
  int j = bj & 2047;
  long kvrow = (long)bj * 2048;
  long obase = (long)bj * 2048;
  for (int t = threadIdx.x; t < 2048; t += 256){
    int h = t >> 7, e = t & 127;
    u16 val = (e < 64) ? kv[kvrow + h*64 + e] : f2b(pe[(long)j*1024 + h*64 + (e - 64)]);
    BB[obase + t] = val;
  }
}

// ---------------------------------------------------------------- gelu(exact) + bias, fp32 in, bf16 out
__global__ __launch_bounds__(256) void gelu_k(const float* __restrict__ f1, const float* __restrict__ b1,
                                              u16* __restrict__ h1)
{
  long i = (long)blockIdx.x*256 + threadIdx.x;
  float x = f1[i] + b1[i & 4095];
  h1[i] = f2b(0.5f * x * (1.f + erff(x * 0.70710678118654752f)));
}

// ---------------------------------------------------------------- out3 = out2 + f2a + f2b + b2  (fp32 out)
__global__ __launch_bounds__(256) void final_k(const float* __restrict__ out2, const float* __restrict__ f2a,
                                               const float* __restrict__ f2b, const float* __restrict__ b2v,
                                               float* __restrict__ outp)
{
  long i = (long)blockIdx.x*256 + threadIdx.x;
  outp[i] = out2[i] + f2a[i] + f2b[i] + b2v[i & 1023];
}

// ================================================================ host
extern "C" void kernel_launch(void* const* d_in, const int* in_sizes, int n_in,
                              void* d_out, int out_size, void* d_ws, size_t ws_size,
                              hipStream_t stream)
{
  (void)in_sizes; (void)n_in; (void)out_size; (void)ws_size;
  // B=2 S=1024 M=1024 St=2048 D=DI=1024 H=16 DH=64 DFF=4096 ; ALL inputs/output fp32
  const float* X    = (const float*)d_in[0];
  const float* ENC  = (const float*)d_in[1];
  const float* PE   = (const float*)d_in[2];
  const float* Uu   = (const float*)d_in[3];
  const float* Vv   = (const float*)d_in[4];
  const float* MEM  = (const float*)d_in[5];
  const float* WQM  = (const float*)d_in[7];
  const float* WKVM = (const float*)d_in[8];
  const float* FCWM = (const float*)d_in[9];
  const float* FCBM = (const float*)d_in[10];
  const float* LNMG = (const float*)d_in[11];
  const float* LNMB = (const float*)d_in[12];
  const float* WQC  = (const float*)d_in[13];
  const float* WKVC = (const float*)d_in[14];
  const float* FCWC = (const float*)d_in[15];
  const float* FCBC = (const float*)d_in[16];
  const float* LNCG = (const float*)d_in[17];
  const float* LNCB = (const float*)d_in[18];
  const float* W1   = (const float*)d_in[19];
  const float* B1   = (const float*)d_in[20];
  const float* W2   = (const float*)d_in[21];
  const float* B2   = (const float*)d_in[22];
  const float* LN1G = (const float*)d_in[23];
  const float* LN1B = (const float*)d_in[24];
  const float* LN2G = (const float*)d_in[25];
  const float* LN2B = (const float*)d_in[26];
  const float* LN3G = (const float*)d_in[27];
  const float* LN3B = (const float*)d_in[28];
  float* OUT = (float*)d_out;
  char* W = (char*)d_ws;
  const size_t MB = 1ull << 20;

  // ---- layout, peak 122 MB (<=136 MB empirically safe)
  // [0,8)    rotating weight region (bf16)
  // [8,12)   xn1 ; [12,16) q -> o_b
  // [16,32)  kv -> outb [24,32)
  // [32,40)  QQ -> xn2 [32,36) + qc [36,40)
  // [40,56)  BB -> kvc [40,48) + Vtc [48,52) + oc [52,56)
  // [56,64)  Vt -> w2T
  // [64,64.5) mz (attn softmax stats)
  // [66,98)  f1 / ofc1 [66,74) + ofc2 [74,82) / f2a [66,74) + f2b [74,82)
  // [68,72)  memb/encb (transient, pre-attention)
  // [98,114) h1 ; [114,122) out2b
  u16*   wT_a  = (u16*)(W + 0*MB);
  u16*   wT_b  = (u16*)(W + 2*MB);
  u16*   wT_c  = (u16*)(W + 6*MB);
  u16*   w1T   = (u16*)(W + 0*MB);
  u16*   xn1   = (u16*)(W + 8*MB);
  u16*   q     = (u16*)(W + 12*MB);
  u16*   o_b   = (u16*)(W + 12*MB);
  u16*   kv    = (u16*)(W + 16*MB);
  float* outb  = (float*)(W + 24*MB);
  u16*   QQ    = (u16*)(W + 32*MB);
  u16*   xn2   = (u16*)(W + 32*MB);
  u16*   qc    = (u16*)(W + 36*MB);
  u16*   BB    = (u16*)(W + 40*MB);
  u16*   kvc   = (u16*)(W + 40*MB);
  u16*   Vtc   = (u16*)(W + 48*MB);
  u16*   oc    = (u16*)(W + 52*MB);
  u16*   Vt    = (u16*)(W + 56*MB);
  u16*   w2T   = (u16*)(W + 56*MB);
  float* mzb   = (float*)(W + 64*MB);
  u16*   memb  = (u16*)(W + 68*MB);
  u16*   encb  = (u16*)(W + 68*MB);
  float* ofc1  = (float*)(W + 66*MB);
  float* ofc2  = (float*)(W + 74*MB);
  float* f1    = (float*)(W + 66*MB);
  float* f2a   = (float*)(W + 66*MB);
  float* f2b   = (float*)(W + 74*MB);
  u16*   h1    = (u16*)(W + 98*MB);
  float* out2b = (float*)(W + 114*MB);

  // ================= MHA (Transformer-XL relative attention) =================
  transpose_cvt_k<<<dim3(16,16),256,0,stream>>>(WQM,  wT_a, 1024,1024);
  transpose_cvt_k<<<dim3(32,16),256,0,stream>>>(WKVM, wT_b, 2048,1024);
  transpose_cvt_k<<<dim3(16,16),256,0,stream>>>(FCWM, wT_c, 1024,1024);
  cvt_k<<<2048,256,0,stream>>>(MEM, memb);
  ln_k<<<2048,256,0,stream>>>(X, LN1G, LN1B, xn1);
  gemm_bt<2,2,true><<<dim3(8,16,1),256,0,stream>>>(xn1, wT_a, q, 1024, 1024,1024,1024, 1, 0,0,0,0,0,0);
  gemm_bt<2,2,true><<<dim3(16,8,2),256,0,stream>>>(memb, wT_b, kv, 1024, 1024,1024,2048, 1,
      1048576,0, 0,0, 4194304,0);
  gemm_bt<2,2,true><<<dim3(16,8,2),256,0,stream>>>(xn1, wT_b, kv + (size_t)1024*2048, 1024, 1024,1024,2048, 1,
      1048576,0, 0,0, 4194304,0);
  build_qq<<<2048,256,0,stream>>>(q, Uu, Vv, QQ);
  build_bb<<<4096,256,0,stream>>>(kv, PE, BB);
  transpose_k<<<dim3(1,32,32),256,0,stream>>>(kv + 1024, Vt, 2048, 2048, 16,
      4194304,64, 2097152,131072);
  // fused attention: two-pass, K-dim=128, masked
  attn_passA<128,true><<<dim3(16,32),256,0,stream>>>(BB, QQ, mzb, 2048, 2048, 2048,
      4194304,128, 2097152,128, 16, 0.125f, 65536);
  attn_passB<128,true><<<dim3(8,32),256,0,stream>>>(BB, QQ, Vt, mzb, o_b, 2048,
      2048,2048,2048,1024, 4194304,128, 2097152,128, 2097152,131072, 1048576,64, 16, 0.125f, 65536);
  // ofc = o @ fcw_m (split-K=2) ; out = x + LN_m(xn1 + ofc + fcb_m)
  gemm_bt<2,2,false><<<dim3(8,16,2),256,0,stream>>>(o_b, wT_c, ofc1, 512, 1024,1024,1024, 2,
      0,512, 0,512, 0,2097152);
  add_ln_k<<<2048,256,0,stream>>>(ofc1, ofc2, xn1, FCBM, LNMG, LNMB, X, outb);

  // ================= cross attention =================
  transpose_cvt_k<<<dim3(16,16),256,0,stream>>>(WQC,  wT_a, 1024,1024);
  transpose_cvt_k<<<dim3(32,16),256,0,stream>>>(WKVC, wT_b, 2048,1024);
  transpose_cvt_k<<<dim3(16,16),256,0,stream>>>(FCWC, wT_c, 1024,1024);
  cvt_k<<<2048,256,0,stream>>>(ENC, encb);
  ln_k<<<2048,256,0,stream>>>(outb, LN2G, LN2B, xn2);
  gemm_bt<2,2,true><<<dim3(8,16,1),256,0,stream>>>(xn2, wT_a, qc, 1024, 1024,1024,1024, 1, 0,0,0,0,0,0);
  gemm_bt<2,2,true><<<dim3(16,16,1),256,0,stream>>>(encb, wT_b, kvc, 1024, 1024,1024,2048, 1, 0,0,0,0,0,0);
  transpose_k<<<dim3(1,16,32),256,0,stream>>>(kvc + 1024, Vtc, 2048, 1024, 16,
      2097152,64, 1048576,65536);
  attn_passA<64,false><<<dim3(8,32),256,0,stream>>>(kvc, qc, mzb, 1024, 2048, 1024,
      2097152,64, 1048576,64, 16, 0.125f, 32768);
  attn_passB<64,false><<<dim3(8,32),256,0,stream>>>(kvc, qc, Vtc, mzb, oc, 1024,
      2048,1024,1024,1024, 2097152,64, 1048576,64, 1048576,65536, 1048576,64, 16, 0.125f, 32768);
  gemm_bt<2,2,false><<<dim3(8,16,2),256,0,stream>>>(oc, wT_c, ofc1, 512, 1024,1024,1024, 2,
      0,512, 0,512, 0,2097152);
  add_ln_k<<<2048,256,0,stream>>>(ofc1, ofc2, xn2, FCBC, LNCG, LNCB, outb, out2b);

  // ================= FFN =================
  transpose_cvt_k<<<dim3(64,16),256,0,stream>>>(W1, w1T, 4096,1024);
  transpose_cvt_k<<<dim3(16,64),256,0,stream>>>(W2, w2T, 1024,4096);
  ln_k<<<2048,256,0,stream>>>(out2b, LN3G, LN3B, xn2);
  gemm_bt<2,2,false><<<dim3(32,16,1),256,0,stream>>>(xn2, w1T, f1, 1024, 1024,1024,4096, 1, 0,0,0,0,0,0);
  gelu_k<<<32768,256,0,stream>>>(f1, B1, h1);
  gemm_bt<2,2,false><<<dim3(8,16,2),256,0,stream>>>(h1, w2T, f2a, 2048, 4096,4096,1024, 2,
      0,2048, 0,2048, 0,2097152);
  final_k<<<8192,256,0,stream>>>(out2b, f2a, f2b, B2, OUT);
}

// Round 7
// 984.464 us; speedup vs baseline: 5.3053x; 1.1287x over previous
//
#include <hip/hip_runtime.h>

typedef unsigned short u16;
typedef __attribute__((ext_vector_type(4))) unsigned short u16x4;
typedef __attribute__((ext_vector_type(8))) unsigned short u16x8;
typedef __attribute__((ext_vector_type(8))) __bf16 bf16x8;
typedef __attribute__((ext_vector_type(4))) float f32x4;

#define DEV __device__ __forceinline__

DEV float b2f(u16 u){ union{ unsigned int i; float f; } x; x.i = ((unsigned int)u) << 16; return x.f; }
DEV u16 f2b(float f){ unsigned int x = __float_as_uint(f); return (u16)((x + 0x7fffu + ((x >> 16) & 1u)) >> 16); }

// ---------------------------------------------------------------- block reduce (256 thr)
DEV void block_red2(float& s, float& q){
#pragma unroll
  for (int off = 32; off; off >>= 1){ s += __shfl_down(s, off); q += __shfl_down(q, off); }
  __shared__ float sh1[4], sh2[4];
  int lane = threadIdx.x & 63, w = threadIdx.x >> 6;
  if (lane == 0){ sh1[w] = s; sh2[w] = q; }
  __syncthreads();
  s = sh1[0] + sh1[1] + sh1[2] + sh1[3];
  q = sh2[0] + sh2[1] + sh2[2] + sh2[3];
}

// ---------------------------------------------------------------- GEMM  C = A[M,K] * B[N,K]^T
template<int WM, int WN, bool OUTB>
__global__ __launch_bounds__(WM*WN*64) void gemm_bt(
    const u16* __restrict__ A, const u16* __restrict__ Bm, void* __restrict__ Cp,
    int K, int lda, int ldb, int ldc, int Hh,
    long aob, long aoh, long bob, long boh, long cob, long coh)
{
  constexpr int BM = WM*64, BN = WN*64, BK = 64, LSTR = BK + 8;
  __shared__ u16 At[BM*LSTR];
  __shared__ u16 Bt[BN*LSTR];
  int z = blockIdx.z, b_ = z / Hh, h_ = z % Hh;
  const u16* Ab = A + (long)b_*aob + (long)h_*aoh;
  const u16* Bb = Bm + (long)b_*bob + (long)h_*boh;
  long cbase = (long)b_*cob + (long)h_*coh;
  int m0 = blockIdx.y * BM, n0 = blockIdx.x * BN;
  int tid = threadIdx.x, lane = tid & 63, wv = tid >> 6;
  int wm = wv / WN, wn = wv % WN;
  constexpr int T = WM*WN*64;
  f32x4 acc[4][4];
  f32x4 z4 = {0.f, 0.f, 0.f, 0.f};
#pragma unroll
  for (int a = 0; a < 4; a++)
#pragma unroll
    for (int b = 0; b < 4; b++) acc[a][b] = z4;
  int lr = lane & 15, lk8 = (lane >> 4) * 8;
  for (int k0 = 0; k0 < K; k0 += BK){
    __syncthreads();
    for (int idx = tid; idx < BM*8; idx += T){
      int r = idx >> 3, c = (idx & 7) << 3;
      *(u16x8*)&At[r*LSTR + c] = *(const u16x8*)&Ab[(long)(m0 + r)*lda + k0 + c];
    }
    for (int idx = tid; idx < BN*8; idx += T){
      int r = idx >> 3, c = (idx & 7) << 3;
      *(u16x8*)&Bt[r*LSTR + c] = *(const u16x8*)&Bb[(long)(n0 + r)*ldb + k0 + c];
    }
    __syncthreads();
#pragma unroll
    for (int kk = 0; kk < BK; kk += 32){
      bf16x8 af[4], bfr[4];
#pragma unroll
      for (int mi = 0; mi < 4; mi++) af[mi]  = *(bf16x8*)&At[(wm*64 + mi*16 + lr)*LSTR + kk + lk8];
#pragma unroll
      for (int ni = 0; ni < 4; ni++) bfr[ni] = *(bf16x8*)&Bt[(wn*64 + ni*16 + lr)*LSTR + kk + lk8];
#pragma unroll
      for (int mi = 0; mi < 4; mi++)
#pragma unroll
        for (int ni = 0; ni < 4; ni++)
          acc[mi][ni] = __builtin_amdgcn_mfma_f32_16x16x32_bf16(af[mi], bfr[ni], acc[mi][ni], 0, 0, 0);
    }
  }
  int orow = (lane >> 4) * 4, ocol = lane & 15;
#pragma unroll
  for (int mi = 0; mi < 4; mi++)
#pragma unroll
    for (int ni = 0; ni < 4; ni++){
      int row = m0 + wm*64 + mi*16 + orow;
      int col = n0 + wn*64 + ni*16 + ocol;
      long cidx = cbase + (long)row*ldc + col;
#pragma unroll
      for (int r = 0; r < 4; r++){
        float vv = acc[mi][ni][r];
        if (OUTB) ((u16*)Cp)[cidx + (long)r*ldc] = f2b(vv);
        else      ((float*)Cp)[cidx + (long)r*ldc] = vv;
      }
    }
}

// ---------------------------------------------------------------- fused attention, query-axis softmax
// Pass A: per (b,h,j-tile of 64): m_j, 1/Z_j over all i (masked). 4 waves x 16 j-rows.
template<int KD, bool MASK>
__global__ __launch_bounds__(256) void attn_passA(
    const u16* __restrict__ Kp, const u16* __restrict__ Qp, float* __restrict__ mz,
    int J, int kld, int qld,
    long kob, long koh, long qob, long qoh, int H, float scale, int mztot)
{
  constexpr int KP = KD + 8;
  __shared__ u16 Kt[64*KP];
  __shared__ u16 Qt[128*KP];
  int bh = blockIdx.y, b = bh / H, h = bh % H;
  const u16* Kb = Kp + (long)b*kob + (long)h*koh;
  const u16* Qb = Qp + (long)b*qob + (long)h*qoh;
  int j0 = blockIdx.x * 64;
  int tid = threadIdx.x, lane = tid & 63, w = tid >> 6;
  int lr = lane & 15, lk8 = (lane >> 4) * 8;
  constexpr int RCH = KD / 8;
  for (int idx = tid; idx < 64*RCH; idx += 256){
    int r = idx / RCH, c = (idx % RCH) * 8;
    *(u16x8*)&Kt[r*KP + c] = *(const u16x8*)&Kb[(long)(j0 + r)*kld + c];
  }
  float m_run[4], z_run[4];
#pragma unroll
  for (int r = 0; r < 4; r++){ m_run[r] = -3.0e38f; z_run[r] = 0.f; }
  f32x4 zz = {0.f,0.f,0.f,0.f};
  for (int it = 0; it < 8; it++){
    if (MASK && (it*128 + 127 < j0 - 1024)) continue;   // i-tile fully masked (uniform)
    __syncthreads();
    for (int idx = tid; idx < 128*RCH; idx += 256){
      int r = idx / RCH, c = (idx % RCH) * 8;
      *(u16x8*)&Qt[r*KP + c] = *(const u16x8*)&Qb[(long)(it*128 + r)*qld + c];
    }
    __syncthreads();
    f32x4 acc[8];
#pragma unroll
    for (int ni = 0; ni < 8; ni++) acc[ni] = zz;
#pragma unroll
    for (int kk = 0; kk < KD; kk += 32){
      bf16x8 af, bq[8];
      af = *(bf16x8*)&Kt[(w*16 + lr)*KP + kk + lk8];
#pragma unroll
      for (int ni = 0; ni < 8; ni++) bq[ni] = *(bf16x8*)&Qt[(ni*16 + lr)*KP + kk + lk8];
#pragma unroll
      for (int ni = 0; ni < 8; ni++)
        acc[ni] = __builtin_amdgcn_mfma_f32_16x16x32_bf16(af, bq[ni], acc[ni], 0, 0, 0);
    }
#pragma unroll
    for (int r = 0; r < 4; r++){
      int jg = j0 + w*16 + ((lane >> 4) << 2) + r;
      float sv[8]; float tm = -3.0e38f;
#pragma unroll
      for (int ni = 0; ni < 8; ni++){
        int ig = it*128 + ni*16 + (lane & 15);
        float s = acc[ni][r] * scale;
        bool val = (!MASK) || (ig >= jg - 1024);
        sv[ni] = val ? s : -3.0e38f;
        tm = fmaxf(tm, sv[ni]);
      }
#pragma unroll
      for (int off = 1; off < 16; off <<= 1) tm = fmaxf(tm, __shfl_xor(tm, off));
      float mn = fmaxf(m_run[r], tm);
      float zt = 0.f;
#pragma unroll
      for (int ni = 0; ni < 8; ni++)
        zt += (sv[ni] > -1.0e37f) ? __expf(sv[ni] - mn) : 0.f;
#pragma unroll
      for (int off = 1; off < 16; off <<= 1) zt += __shfl_xor(zt, off);
      z_run[r] = z_run[r] * __expf(m_run[r] - mn) + zt;
      m_run[r] = mn;
    }
  }
  if ((lane & 15) == 0){
#pragma unroll
    for (int r = 0; r < 4; r++){
      int jg = j0 + w*16 + ((lane >> 4) << 2) + r;
      mz[(long)bh*J + jg] = m_run[r];
      mz[(long)mztot + (long)bh*J + jg] = 1.f / z_run[r];
    }
  }
}

// Pass B: per (b,h,i-tile of 64): o[i,d] = sum_j exp(s*scale - m_j)/Z_j * V[j,d].
// 4 waves x 16 i-rows; K/V tiles of 128 j. P through LDS (C-layout -> A-layout).
template<int KD, bool MASK>
__global__ __launch_bounds__(256) void attn_passB(
    const u16* __restrict__ Kp, const u16* __restrict__ Qp, const u16* __restrict__ Vtp,
    const float* __restrict__ mz, u16* __restrict__ Op,
    int J, int kld, int qld, int vld, int oldd,
    long kob, long koh, long qob, long qoh, long vob, long voh, long oob, long ooh,
    int H, float scale, int mztot)
{
  constexpr int KP = KD + 8, PSTR = 140, VSTR = 136;
  __shared__ u16 Qt[64*KP];
  __shared__ u16 PK[128*KP];       // K tile (128 x KP) ; aliased by P tile (64 x PSTR)
  __shared__ u16 Vtt[64*VSTR];
  u16* Kt = PK;
  u16* Pt = PK;
  int bh = blockIdx.y, b = bh / H, h = bh % H;
  const u16* Kb = Kp + (long)b*kob + (long)h*koh;
  const u16* Qb = Qp + (long)b*qob + (long)h*qoh;
  const u16* Vb = Vtp + (long)b*vob + (long)h*voh;
  u16* Ob = Op + (long)b*oob + (long)h*ooh;
  const float* mzm = mz + (long)bh*J;
  const float* mzz = mz + (long)mztot + (long)bh*J;
  int i0 = blockIdx.x * 64;
  int tid = threadIdx.x, lane = tid & 63, w = tid >> 6;
  int lr = lane & 15, lk8 = (lane >> 4) * 8;
  constexpr int RCH = KD / 8;
  for (int idx = tid; idx < 64*RCH; idx += 256){
    int r = idx / RCH, c = (idx % RCH) * 8;
    *(u16x8*)&Qt[r*KP + c] = *(const u16x8*)&Qb[(long)(i0 + r)*qld + c];
  }
  f32x4 acc_o[4];
  f32x4 zz = {0.f,0.f,0.f,0.f};
#pragma unroll
  for (int nd = 0; nd < 4; nd++) acc_o[nd] = zz;
  int JT = J >> 7;
  for (int jt = 0; jt < JT; jt++){
    if (MASK && (jt*128 > i0 + 1087)) continue;    // j-tile fully masked (uniform)
    __syncthreads();                               // prior P/Vt reads done before restage
    for (int idx = tid; idx < 128*RCH; idx += 256){
      int r = idx / RCH, c = (idx % RCH) * 8;
      *(u16x8*)&Kt[r*KP + c] = *(const u16x8*)&Kb[(long)(jt*128 + r)*kld + c];
    }
    for (int idx = tid; idx < 64*16; idx += 256){
      int r = idx >> 4, c = (idx & 15) << 3;
      *(u16x8*)&Vtt[r*VSTR + c] = *(const u16x8*)&Vb[(long)r*vld + jt*128 + c];
    }
    __syncthreads();
    // S tile: A = Q (own wave's 16 i-rows), B = K (128 j)
    f32x4 acc[8];
#pragma unroll
    for (int ni = 0; ni < 8; ni++) acc[ni] = zz;
#pragma unroll
    for (int kk = 0; kk < KD; kk += 32){
      bf16x8 aq, bk[8];
      aq = *(bf16x8*)&Qt[(w*16 + lr)*KP + kk + lk8];
#pragma unroll
      for (int ni = 0; ni < 8; ni++) bk[ni] = *(bf16x8*)&Kt[(ni*16 + lr)*KP + kk + lk8];
#pragma unroll
      for (int ni = 0; ni < 8; ni++)
        acc[ni] = __builtin_amdgcn_mfma_f32_16x16x32_bf16(aq, bk[ni], acc[ni], 0, 0, 0);
    }
    __syncthreads();                               // K reads done before P overwrite (alias)
#pragma unroll
    for (int ni = 0; ni < 8; ni++){
      int jg = jt*128 + ni*16 + (lane & 15);
      float mj = mzm[jg], zj = mzz[jg];
#pragma unroll
      for (int r = 0; r < 4; r++){
        int ig = i0 + w*16 + ((lane >> 4) << 2) + r;
        bool val = (!MASK) || (ig >= jg - 1024);
        float p = val ? __expf(acc[ni][r] * scale - mj) * zj : 0.f;
        Pt[(w*16 + ((lane >> 4) << 2) + r)*PSTR + ni*16 + (lane & 15)] = f2b(p);
      }
    }
    __syncthreads();
    // PV: A = P (own wave's 16 i-rows), B = Vt (64 d-rows)
#pragma unroll
    for (int kk = 0; kk < 128; kk += 32){
      bf16x8 pa, vb[4];
      pa = *(bf16x8*)&Pt[(w*16 + lr)*PSTR + kk + lk8];
#pragma unroll
      for (int nd = 0; nd < 4; nd++) vb[nd] = *(bf16x8*)&Vtt[(nd*16 + lr)*VSTR + kk + lk8];
#pragma unroll
      for (int nd = 0; nd < 4; nd++)
        acc_o[nd] = __builtin_amdgcn_mfma_f32_16x16x32_bf16(pa, vb[nd], acc_o[nd], 0, 0, 0);
    }
  }
#pragma unroll
  for (int nd = 0; nd < 4; nd++)
#pragma unroll
    for (int r = 0; r < 4; r++){
      int ig = i0 + w*16 + ((lane >> 4) << 2) + r;
      int d = nd*16 + (lane & 15);
      Ob[(long)ig*oldd + d] = f2b(acc_o[nd][r]);
    }
}

// ---------------------------------------------------------------- bf16 transpose dst[c,r]=src[r,c]
__global__ __launch_bounds__(256) void transpose_k(
    const u16* __restrict__ src, u16* __restrict__ dst,
    int lds_, int ldd, int Hh, long sob, long soh, long dob, long doh)
{
  __shared__ u16 tile[64*72];
  int z = blockIdx.z, b_ = z / Hh, h_ = z % Hh;
  const u16* S_ = src + (long)b_*sob + (long)h_*soh;
  u16* D_ = dst + (long)b_*dob + (long)h_*doh;
  int r0 = blockIdx.y * 64, c0 = blockIdx.x * 64;
  int tid = threadIdx.x;
  for (int idx = tid; idx < 512; idx += 256){
    int r = idx >> 3, c = (idx & 7) << 3;
    *(u16x8*)&tile[r*72 + c] = *(const u16x8*)&S_[(long)(r0 + r)*lds_ + c0 + c];
  }
  __syncthreads();
  for (int idx = tid; idx < 512; idx += 256){
    int c = idx >> 3, r = (idx & 7) << 3;
    u16x8 v;
#pragma unroll
    for (int e = 0; e < 8; e++) v[e] = tile[(r + e)*72 + c];
    *(u16x8*)&D_[(long)(c0 + c)*ldd + r0 + r] = v;
  }
}

// ---------------------------------------------------------------- fp32 src -> bf16 transposed dst
__global__ __launch_bounds__(256) void transpose_cvt_k(
    const float* __restrict__ src, u16* __restrict__ dst, int lds_, int ldd)
{
  __shared__ u16 tile[64*72];
  int r0 = blockIdx.y * 64, c0 = blockIdx.x * 64;
  int tid = threadIdx.x;
  for (int idx = tid; idx < 512; idx += 256){
    int r = idx >> 3, c = (idx & 7) << 3;
    const float* s = &src[(long)(r0 + r)*lds_ + c0 + c];
#pragma unroll
    for (int e = 0; e < 8; e++) tile[r*72 + c + e] = f2b(s[e]);
  }
  __syncthreads();
  for (int idx = tid; idx < 512; idx += 256){
    int c = idx >> 3, r = (idx & 7) << 3;
    u16x8 v;
#pragma unroll
    for (int e = 0; e < 8; e++) v[e] = tile[(r + e)*72 + c];
    *(u16x8*)&dst[(long)(c0 + c)*ldd + r0 + r] = v;
  }
}

// ---------------------------------------------------------------- flat fp32 -> bf16
__global__ __launch_bounds__(256) void cvt_k(const float* __restrict__ src, u16* __restrict__ dst)
{
  long i = ((long)blockIdx.x*256 + threadIdx.x) * 4;
  float4 v = *(const float4*)&src[i];
  u16x4 o; o[0] = f2b(v.x); o[1] = f2b(v.y); o[2] = f2b(v.z); o[3] = f2b(v.w);
  *(u16x4*)&dst[i] = o;
}

// ---------------------------------------------------------------- LayerNorm row=1024, fp32 in, bf16 out
__global__ __launch_bounds__(256) void ln_k(const float* __restrict__ src, const float* __restrict__ g,
                                            const float* __restrict__ be, u16* __restrict__ out)
{
  long base = (long)blockIdx.x * 1024;
  int tid = threadIdx.x;
  const float* s = src + base + tid*4;
  float v[4] = {s[0], s[1], s[2], s[3]};
  float s1 = v[0]+v[1]+v[2]+v[3];
  float s2 = v[0]*v[0]+v[1]*v[1]+v[2]*v[2]+v[3]*v[3];
  block_red2(s1, s2);
  float mu = s1 * (1.f/1024.f);
  float var = s2 * (1.f/1024.f) - mu*mu;
  float rs = rsqrtf(var + 1e-5f);
#pragma unroll
  for (int e = 0; e < 4; e++){
    int col = tid*4 + e;
    out[base + col] = f2b((v[e]-mu)*rs*g[col] + be[col]);
  }
}

// ---------------------------------------------------------------- out = resid + LN(sum4(go) + xn + bias)  (fp32 out)
__global__ __launch_bounds__(256) void add_ln_k(const float* __restrict__ go,
    const u16* __restrict__ xn, const float* __restrict__ bias,
    const float* __restrict__ g, const float* __restrict__ be,
    const float* __restrict__ resid, float* __restrict__ outp)
{
  const long PS = 2097152;
  long base = (long)blockIdx.x * 1024;
  int tid = threadIdx.x;
  float v[4];
#pragma unroll
  for (int e = 0; e < 4; e++){
    int col = tid*4 + e;
    long idx = base + col;
    v[e] = go[idx] + go[idx + PS] + go[idx + 2*PS] + go[idx + 3*PS] + b2f(xn[idx]) + bias[col];
  }
  float s1 = v[0]+v[1]+v[2]+v[3];
  float s2 = v[0]*v[0]+v[1]*v[1]+v[2]*v[2]+v[3]*v[3];
  block_red2(s1, s2);
  float mu = s1 * (1.f/1024.f);
  float var = s2 * (1.f/1024.f) - mu*mu;
  float rs = rsqrtf(var + 1e-5f);
#pragma unroll
  for (int e = 0; e < 4; e++){
    int col = tid*4 + e;
    outp[base + col] = resid[base + col] + (v[e]-mu)*rs*g[col] + be[col];
  }
}

// ---------------------------------------------------------------- QQ = [q+u | shifted(q+v)]  (B,S,H,128)
__global__ __launch_bounds__(256) void build_qq(const u16* __restrict__ q, const float* __restrict__ u,
                                                const float* __restrict__ v, u16* __restrict__ QQ)
{
  int bi = blockIdx.x;
  long qrow = (long)bi * 1024;
  long obase = (long)bi * 2048;
  int n = bi + 2;
  int bp = n / 1025, ip = n % 1025;
  long qsrc = ip ? ((long)(bp*1024 + ip - 1)) * 1024 : -1;
  for (int t = threadIdx.x; t < 2048; t += 256){
    int h = t >> 7, e = t & 127;
    float val;
    if (e < 64) val = b2f(q[qrow + h*64 + e]) + u[h*64 + e];
    else {
      int d = e - 64;
      val = (qsrc < 0) ? 0.f : b2f(q[qsrc + h*64 + d]) + v[h*64 + d];
    }
    QQ[obase + t] = f2b(val);
  }
}

// ---------------------------------------------------------------- BB = [k | pos_emb]  (B,St,H,128)
__global__ __launch_bounds__(256) void build_bb(const u16* __restrict__ kv, const float* __restrict__ pe,
                                                u16* __restrict__ BB)
{
  int bj = blockIdx.x;
  int j = bj & 2047;
  long kvrow = (long)bj * 2048;
  long obase = (long)bj * 2048;
  for (int t = threadIdx.x; t < 2048; t += 256){
    int h = t >> 7, e = t & 127;
    u16 val = (e < 64) ? kv[kvrow + h*64 + e] : f2b(pe[(long)j*1024 + h*64 + (e - 64)]);
    BB[obase + t] = val;
  }
}

// ---------------------------------------------------------------- gelu(exact) + bias, fp32 in, bf16 out
__global__ __launch_bounds__(256) void gelu_k(const float* __restrict__ f1, const float* __restrict__ b1,
                                              u16* __restrict__ h1)
{
  long i = (long)blockIdx.x*256 + threadIdx.x;
  float x = f1[i] + b1[i & 4095];
  h1[i] = f2b(0.5f * x * (1.f + erff(x * 0.70710678118654752f)));
}

// ---------------------------------------------------------------- out3 = out2 + sum4(f2) + b2  (fp32 out)
__global__ __launch_bounds__(256) void final_k(const float* __restrict__ out2, const float* __restrict__ f2,
                                               const float* __restrict__ b2v, float* __restrict__ outp)
{
  const long PS = 2097152;
  long i = (long)blockIdx.x*256 + threadIdx.x;
  outp[i] = out2[i] + f2[i] + f2[i + PS] + f2[i + 2*PS] + f2[i + 3*PS] + b2v[i & 1023];
}

// ================================================================ host
extern "C" void kernel_launch(void* const* d_in, const int* in_sizes, int n_in,
                              void* d_out, int out_size, void* d_ws, size_t ws_size,
                              hipStream_t stream)
{
  (void)in_sizes; (void)n_in; (void)out_size; (void)ws_size;
  // B=2 S=1024 M=1024 St=2048 D=DI=1024 H=16 DH=64 DFF=4096 ; ALL inputs/output fp32
  const float* X    = (const float*)d_in[0];
  const float* ENC  = (const float*)d_in[1];
  const float* PE   = (const float*)d_in[2];
  const float* Uu   = (const float*)d_in[3];
  const float* Vv   = (const float*)d_in[4];
  const float* MEM  = (const float*)d_in[5];
  const float* WQM  = (const float*)d_in[7];
  const float* WKVM = (const float*)d_in[8];
  const float* FCWM = (const float*)d_in[9];
  const float* FCBM = (const float*)d_in[10];
  const float* LNMG = (const float*)d_in[11];
  const float* LNMB = (const float*)d_in[12];
  const float* WQC  = (const float*)d_in[13];
  const float* WKVC = (const float*)d_in[14];
  const float* FCWC = (const float*)d_in[15];
  const float* FCBC = (const float*)d_in[16];
  const float* LNCG = (const float*)d_in[17];
  const float* LNCB = (const float*)d_in[18];
  const float* W1   = (const float*)d_in[19];
  const float* B1   = (const float*)d_in[20];
  const float* W2   = (const float*)d_in[21];
  const float* B2   = (const float*)d_in[22];
  const float* LN1G = (const float*)d_in[23];
  const float* LN1B = (const float*)d_in[24];
  const float* LN2G = (const float*)d_in[25];
  const float* LN2B = (const float*)d_in[26];
  const float* LN3G = (const float*)d_in[27];
  const float* LN3B = (const float*)d_in[28];
  float* OUT = (float*)d_out;
  char* W = (char*)d_ws;
  const size_t MB = 1ull << 20;

  // ---- layout, peak 122 MB
  // [0,8)    rotating weight region (bf16)
  // [8,12)   xn1 ; [12,16) q -> o_b
  // [16,32)  kv -> outb [24,32)
  // [32,40)  QQ -> xn2 [32,36) + qc [36,40)
  // [40,56)  BB -> kvc [40,48) + Vtc [48,52) + oc [52,56)
  // [56,64)  Vt -> w2T
  // [64,66)  mz (attn softmax stats)
  // [66,98)  ofc partials x4 / f1 / f2 partials x4
  // [68,72)  memb/encb (transient, pre-attention)
  // [98,114) h1 ; [114,122) out2b
  u16*   wT_a  = (u16*)(W + 0*MB);
  u16*   wT_b  = (u16*)(W + 2*MB);
  u16*   wT_c  = (u16*)(W + 6*MB);
  u16*   w1T   = (u16*)(W + 0*MB);
  u16*   xn1   = (u16*)(W + 8*MB);
  u16*   q     = (u16*)(W + 12*MB);
  u16*   o_b   = (u16*)(W + 12*MB);
  u16*   kv    = (u16*)(W + 16*MB);
  float* outb  = (float*)(W + 24*MB);
  u16*   QQ    = (u16*)(W + 32*MB);
  u16*   xn2   = (u16*)(W + 32*MB);
  u16*   qc    = (u16*)(W + 36*MB);
  u16*   BB    = (u16*)(W + 40*MB);
  u16*   kvc   = (u16*)(W + 40*MB);
  u16*   Vtc   = (u16*)(W + 48*MB);
  u16*   oc    = (u16*)(W + 52*MB);
  u16*   Vt    = (u16*)(W + 56*MB);
  u16*   w2T   = (u16*)(W + 56*MB);
  float* mzb   = (float*)(W + 64*MB);
  u16*   memb  = (u16*)(W + 68*MB);
  u16*   encb  = (u16*)(W + 68*MB);
  float* ofc   = (float*)(W + 66*MB);    // 4 partials x 8 MB
  float* f1    = (float*)(W + 66*MB);
  float* f2    = (float*)(W + 66*MB);    // 4 partials x 8 MB
  u16*   h1    = (u16*)(W + 98*MB);
  float* out2b = (float*)(W + 114*MB);

  // ================= MHA (Transformer-XL relative attention) =================
  transpose_cvt_k<<<dim3(16,16),256,0,stream>>>(WQM,  wT_a, 1024,1024);
  transpose_cvt_k<<<dim3(32,16),256,0,stream>>>(WKVM, wT_b, 2048,1024);
  transpose_cvt_k<<<dim3(16,16),256,0,stream>>>(FCWM, wT_c, 1024,1024);
  cvt_k<<<2048,256,0,stream>>>(MEM, memb);
  ln_k<<<2048,256,0,stream>>>(X, LN1G, LN1B, xn1);
  gemm_bt<2,2,true><<<dim3(8,16,1),256,0,stream>>>(xn1, wT_a, q, 1024, 1024,1024,1024, 1, 0,0,0,0,0,0);
  gemm_bt<2,2,true><<<dim3(16,8,2),256,0,stream>>>(memb, wT_b, kv, 1024, 1024,1024,2048, 1,
      1048576,0, 0,0, 4194304,0);
  gemm_bt<2,2,true><<<dim3(16,8,2),256,0,stream>>>(xn1, wT_b, kv + (size_t)1024*2048, 1024, 1024,1024,2048, 1,
      1048576,0, 0,0, 4194304,0);
  build_qq<<<2048,256,0,stream>>>(q, Uu, Vv, QQ);
  build_bb<<<4096,256,0,stream>>>(kv, PE, BB);
  transpose_k<<<dim3(1,32,32),256,0,stream>>>(kv + 1024, Vt, 2048, 2048, 16,
      4194304,64, 2097152,131072);
  attn_passA<128,true><<<dim3(32,32),256,0,stream>>>(BB, QQ, mzb, 2048, 2048, 2048,
      4194304,128, 2097152,128, 16, 0.125f, 65536);
  attn_passB<128,true><<<dim3(16,32),256,0,stream>>>(BB, QQ, Vt, mzb, o_b, 2048,
      2048,2048,2048,1024, 4194304,128, 2097152,128, 2097152,131072, 1048576,64, 16, 0.125f, 65536);
  // ofc = o @ fcw_m (split-K=4) ; out = x + LN_m(xn1 + ofc + fcb_m)
  gemm_bt<2,2,false><<<dim3(8,16,4),256,0,stream>>>(o_b, wT_c, ofc, 256, 1024,1024,1024, 4,
      0,256, 0,256, 0,2097152);
  add_ln_k<<<2048,256,0,stream>>>(ofc, xn1, FCBM, LNMG, LNMB, X, outb);

  // ================= cross attention =================
  transpose_cvt_k<<<dim3(16,16),256,0,stream>>>(WQC,  wT_a, 1024,1024);
  transpose_cvt_k<<<dim3(32,16),256,0,stream>>>(WKVC, wT_b, 2048,1024);
  transpose_cvt_k<<<dim3(16,16),256,0,stream>>>(FCWC, wT_c, 1024,1024);
  cvt_k<<<2048,256,0,stream>>>(ENC, encb);
  ln_k<<<2048,256,0,stream>>>(outb, LN2G, LN2B, xn2);
  gemm_bt<2,2,true><<<dim3(8,16,1),256,0,stream>>>(xn2, wT_a, qc, 1024, 1024,1024,1024, 1, 0,0,0,0,0,0);
  gemm_bt<2,2,true><<<dim3(16,16,1),256,0,stream>>>(encb, wT_b, kvc, 1024, 1024,1024,2048, 1, 0,0,0,0,0,0);
  transpose_k<<<dim3(1,16,32),256,0,stream>>>(kvc + 1024, Vtc, 2048, 1024, 16,
      2097152,64, 1048576,65536);
  attn_passA<64,false><<<dim3(16,32),256,0,stream>>>(kvc, qc, mzb, 1024, 2048, 1024,
      2097152,64, 1048576,64, 16, 0.125f, 32768);
  attn_passB<64,false><<<dim3(16,32),256,0,stream>>>(kvc, qc, Vtc, mzb, oc, 1024,
      2048,1024,1024,1024, 2097152,64, 1048576,64, 1048576,65536, 1048576,64, 16, 0.125f, 32768);
  gemm_bt<2,2,false><<<dim3(8,16,4),256,0,stream>>>(oc, wT_c, ofc, 256, 1024,1024,1024, 4,
      0,256, 0,256, 0,2097152);
  add_ln_k<<<2048,256,0,stream>>>(ofc, xn2, FCBC, LNCG, LNCB, outb, out2b);

  // ================= FFN =================
  transpose_cvt_k<<<dim3(64,16),256,0,stream>>>(W1, w1T, 4096,1024);
  transpose_cvt_k<<<dim3(16,64),256,0,stream>>>(W2, w2T, 1024,4096);
  ln_k<<<2048,256,0,stream>>>(out2b, LN3G, LN3B, xn2);
  gemm_bt<2,2,false><<<dim3(32,16,1),256,0,stream>>>(xn2, w1T, f1, 1024, 1024,1024,4096, 1, 0,0,0,0,0,0);
  gelu_k<<<32768,256,0,stream>>>(f1, B1, h1);
  gemm_bt<2,2,false><<<dim3(8,16,4),256,0,stream>>>(h1, w2T, f2, 1024, 4096,4096,1024, 4,
      0,1024, 0,1024, 0,2097152);
  final_k<<<8192,256,0,stream>>>(out2b, f2, B2, OUT);
}